// Round 11
// baseline (862.310 us; speedup 1.0000x reference)
//
#include <hip/hip_runtime.h>
#include <hip/hip_bf16.h>
#include <math.h>

typedef __hip_bfloat16 bf16;
typedef unsigned short u16;
typedef __bf16 bf16x8 __attribute__((ext_vector_type(8)));
typedef float f32x4 __attribute__((ext_vector_type(4)));

// ---------- helpers ----------
__device__ __forceinline__ float b2f(bf16 v) { return __bfloat162float(v); }
__device__ __forceinline__ bf16 f2b(float v) { return __float2bfloat16(v); }
__device__ __forceinline__ float bits2f(unsigned int u) {
    union { unsigned int i; float f; } w; w.i = u << 16; return w.f;
}
__device__ __forceinline__ u16 f2bits(float v) {
    union { bf16 h; u16 u; } w; w.h = __float2bfloat16(v); return w.u;
}
__device__ __forceinline__ void async16(void* lds, const void* g) {
    __builtin_amdgcn_global_load_lds(
        (const __attribute__((address_space(1))) unsigned int*)g,
        (__attribute__((address_space(3))) unsigned int*)lds, 16, 0, 0);
}

#define DEPTH 4
#define HEADS 8
#define DHEAD 64
#define DIM 512
#define MLPD 2048
#define RED 128
#define BB 8
#define PP 4
#define NN 256
#define ROWS (BB*PP*NN)          // 8192 tokens
#define XELEMS ((size_t)ROWS*DIM) // 4194304

// ---------- fused batched weight transpose+cast, ALL 7 weights in one launch ----------
__global__ __launch_bounds__(256)
void wtrans_fused(const float* __restrict__ Wqkv, u16* __restrict__ Tqkv,
                  const float* __restrict__ Wo,   u16* __restrict__ To,
                  const float* __restrict__ W1,   u16* __restrict__ T1,
                  const float* __restrict__ W2,   u16* __restrict__ T2,
                  const float* __restrict__ Wl,   u16* __restrict__ Tl,
                  const float* __restrict__ Wg,   u16* __restrict__ Tg,
                  const float* __restrict__ Wc,   u16* __restrict__ Tc)
{
    __shared__ float T[32][33];
    const int x = blockIdx.x, l = blockIdx.z;
    const float* W; u16* WT; int K, N, nx, local;
    if      (x < 768)  { W=Wqkv; WT=Tqkv; K=512;  N=1536; nx=48; local=x; }
    else if (x < 1024) { W=Wo;   WT=To;   K=512;  N=512;  nx=16; local=x-768; }
    else if (x < 2048) { W=W1;   WT=T1;   K=512;  N=2048; nx=64; local=x-1024; }
    else if (x < 3072) { W=W2;   WT=T2;   K=2048; N=512;  nx=16; local=x-2048; }
    else if (x < 3136) { W=Wl;   WT=Tl;   K=512;  N=128;  nx=4;  local=x-3072; }
    else if (x < 3200) { W=Wg;   WT=Tg;   K=512;  N=128;  nx=4;  local=x-3136; }
    else               { W=Wc;   WT=Tc;   K=128;  N=512;  nx=16; local=x-3200; }
    W  += (size_t)l * K * N;
    WT += (size_t)l * N * K;
    const int n0 = (local % nx) * 32, k0 = (local / nx) * 32;
    const int tx = threadIdx.x & 31, ty = threadIdx.x >> 5;
#pragma unroll
    for (int r = 0; r < 4; ++r)
        T[ty + r*8][tx] = W[(size_t)(k0 + ty + r*8) * N + n0 + tx];
    __syncthreads();
#pragma unroll
    for (int r = 0; r < 4; ++r)
        WT[(size_t)(n0 + ty + r*8) * K + k0 + tx] = f2bits(T[tx][ty + r*8]);
}

// ---------- double-buffered MFMA GEMM (2-phase): C = act(A @ WT^T + bias) [+res]
template<int BM, int BN, int BK, int WROWS, int WCOLS>
__global__ __launch_bounds__(256)
void gemm_db(const u16* __restrict__ A, const u16* __restrict__ WT,
             const float* __restrict__ bias, const float* __restrict__ res,
             void* __restrict__ Cv, int M, int N, int K, int act, int outf32)
{
    constexpr int KG  = BK/8;        // 16B k-groups per row
    constexpr int RPC = 512/BK;      // rows per 1KB staging chunk
    constexpr int NCA = BM*BK/512;   // A chunks
    constexpr int NCB = BN*BK/512;   // B chunks
    constexpr int CPT = (NCA+NCB)/4; // chunks per wave
    constexpr int WM = BM/WROWS, WN = BN/WCOLS;
    constexpr int AM = WM/16, AN = WN/16, KB = BK/32;

    __shared__ u16 As[2][BM*BK];
    __shared__ u16 Bs[2][BN*BK];
    const int tid = threadIdx.x, wave = tid >> 6, lane = tid & 63;
    const int bm = blockIdx.x * BM;
    const int bn = blockIdx.y * BN;
    const int wm = (wave / WCOLS) * WM, wn = (wave % WCOLS) * WN;
    const int lr = lane & 15, quad = lane >> 4;

    const int rowc = lane / KG;
    const int kgs  = ((lane & (KG-1)) ^ (KG == 4 ? ((rowc >> 1) & 3) : (rowc & 7))) * 8;

    auto stage = [&](int buf, int k0) {
#pragma unroll
        for (int t = 0; t < CPT; ++t) {
            const int c = wave*CPT + t;
            if (c < NCA)
                async16(&As[buf][c*512], A  + (size_t)(bm + c*RPC + rowc) * K + k0 + kgs);
            else
                async16(&Bs[buf][(c-NCA)*512], WT + (size_t)(bn + (c-NCA)*RPC + rowc) * K + k0 + kgs);
        }
    };

    f32x4 acc[AM][AN] = {};

    stage(0, 0);
    __syncthreads();

    const int NK = K / BK;
    for (int ki = 0; ki < NK; ++ki) {
        const int cur = ki & 1;
        if (ki + 1 < NK) stage(cur ^ 1, (ki + 1) * BK);

        bf16x8 af[AM][KB], bv[AN][KB];
#pragma unroll
        for (int i = 0; i < AM; ++i) {
            const int rA = wm + i*16 + lr;
            const int sw = (KG == 4 ? (((rA & 15) >> 1) & 3) : (rA & 7));
#pragma unroll
            for (int kb = 0; kb < KB; ++kb)
                af[i][kb] = *(const bf16x8*)(As[cur] + rA*BK + (((kb*4 + quad) ^ sw) * 8));
        }
#pragma unroll
        for (int j = 0; j < AN; ++j) {
            const int rB = wn + j*16 + lr;
            const int sw = (KG == 4 ? (((rB & 15) >> 1) & 3) : (rB & 7));
#pragma unroll
            for (int kb = 0; kb < KB; ++kb)
                bv[j][kb] = *(const bf16x8*)(Bs[cur] + rB*BK + (((kb*4 + quad) ^ sw) * 8));
        }
#pragma unroll
        for (int i = 0; i < AM; ++i)
#pragma unroll
            for (int j = 0; j < AN; ++j)
#pragma unroll
                for (int kb = 0; kb < KB; ++kb)
                    acc[i][j] = __builtin_amdgcn_mfma_f32_16x16x32_bf16(
                        af[i][kb], bv[j][kb], acc[i][j], 0, 0, 0);
        __syncthreads();
    }

#pragma unroll
    for (int i = 0; i < AM; ++i) {
        const int rowb = bm + wm + i*16 + quad*4;
#pragma unroll
        for (int j = 0; j < AN; ++j) {
            const int col = bn + wn + j*16 + lr;
            const float bvs = bias ? bias[col] : 0.f;
#pragma unroll
            for (int r = 0; r < 4; ++r) {
                float v = acc[i][j][r] + bvs;
                if (act == 1) v = 0.5f * v * (1.0f + erff(v * 0.70710678118f));
                else if (act == 2) v = 1.0f / (1.0f + __expf(-v));
                const size_t idx = (size_t)(rowb + r) * N + col;
                if (res) v += res[idx];
                if (outf32) ((float*)Cv)[idx] = v;
                else        ((u16*)Cv)[idx] = f2bits(v);
            }
        }
    }
}

// ---------- 8-phase 256x256 MFMA GEMM (T3+T4 counted vmcnt, T5 setprio) ----------
// Clean m201-style schedule: per-phase {ds_read -> s_barrier -> lgkmcnt(0) ->
// sched_barrier(0) [rule #18 only] -> setprio(1) MFMA setprio(0) -> s_barrier};
// vmcnt(8) once per K-tile (counted, never 0 in main loop). No other fences.
__global__ __launch_bounds__(512, 1)
void gemm_8ph(const u16* __restrict__ A, const u16* __restrict__ WT,
              const float* __restrict__ bias, const float* __restrict__ res,
              void* __restrict__ Cv, int M, int N, int K, int act, int outf32)
{
    __shared__ u16 As[2][256*64];   // 64 KB
    __shared__ u16 Bs[2][256*64];   // 64 KB -> 128 KB total, 1 block/CU
    const int tid = threadIdx.x, wave = tid >> 6, lane = tid & 63;
    const int bm = blockIdx.x * 256;
    const int bn = blockIdx.y * 256;
    const int wm = (wave >> 2) * 128;      // 2 wave-rows
    const int wn = (wave & 3) * 64;        // 4 wave-cols
    const int lr = lane & 15, quad = lane >> 4;

    // staging: 8 16B-groups per 64-elem row; 8 rows per 1KB chunk
    const int rowc = lane >> 3;
    const int kgs  = ((lane & 7) ^ (rowc & 7)) * 8;

    // waves 0-3 stage the 32 A-chunks, waves 4-7 the 32 B-chunks: 8 loads/wave/tile
    auto stage = [&](int buf, int k0) {
        if (wave < 4) {
#pragma unroll
            for (int t = 0; t < 8; ++t) {
                const int c = wave*8 + t;
                async16(&As[buf][c*512], A + (size_t)(bm + c*8 + rowc) * K + k0 + kgs);
            }
        } else {
#pragma unroll
            for (int t = 0; t < 8; ++t) {
                const int c = (wave - 4)*8 + t;
                async16(&Bs[buf][c*512], WT + (size_t)(bn + c*8 + rowc) * K + k0 + kgs);
            }
        }
    };

    f32x4 acc[8][4] = {};

    stage(0, 0);
    const int NK = K / 64;
    for (int t = 0; t < NK; ++t) {
        const int cur = t & 1;
        if (t + 1 < NK) {
            stage(cur ^ 1, (t + 1) * 64);                    // 8 loads stay in flight
            asm volatile("s_waitcnt vmcnt(8)" ::: "memory"); // tile t's 8 loads landed
        } else {
            asm volatile("s_waitcnt vmcnt(0)" ::: "memory");
        }
        __builtin_amdgcn_s_barrier();   // all waves past their vmcnt -> LDS tile complete

        // B fragments (shared by all 4 phases)
        bf16x8 bv[4][2];
#pragma unroll
        for (int j = 0; j < 4; ++j) {
            const int rB = wn + j*16 + lr;
            const int sw = rB & 7;
#pragma unroll
            for (int kb = 0; kb < 2; ++kb)
                bv[j][kb] = *(const bf16x8*)(Bs[cur] + rB*64 + (((kb*4 + quad) ^ sw) * 8));
        }

        // 4 phases, each: one C row-quadrant (32 rows x 64 cols) over K=64 -> 16 MFMA
#pragma unroll
        for (int p = 0; p < 4; ++p) {
            bf16x8 af[2][2];
#pragma unroll
            for (int ii = 0; ii < 2; ++ii) {
                const int rA = wm + (p*2 + ii)*16 + lr;
                const int sw = rA & 7;
#pragma unroll
                for (int kb = 0; kb < 2; ++kb)
                    af[ii][kb] = *(const bf16x8*)(As[cur] + rA*64 + (((kb*4 + quad) ^ sw) * 8));
            }
            __builtin_amdgcn_s_barrier();
            asm volatile("s_waitcnt lgkmcnt(0)" ::: "memory");
            __builtin_amdgcn_sched_barrier(0);   // keep MFMA below the wait (rule #18)
            __builtin_amdgcn_s_setprio(1);
#pragma unroll
            for (int ii = 0; ii < 2; ++ii)
#pragma unroll
                for (int j = 0; j < 4; ++j)
#pragma unroll
                    for (int kb = 0; kb < 2; ++kb)
                        acc[p*2 + ii][j] = __builtin_amdgcn_mfma_f32_16x16x32_bf16(
                            af[ii][kb], bv[j][kb], acc[p*2 + ii][j], 0, 0, 0);
            __builtin_amdgcn_s_setprio(0);
            __builtin_amdgcn_s_barrier();        // frees this sub-phase; aligns waves
        }
    }

#pragma unroll
    for (int i = 0; i < 8; ++i) {
        const int rowb = bm + wm + i*16 + quad*4;
#pragma unroll
        for (int j = 0; j < 4; ++j) {
            const int col = bn + wn + j*16 + lr;
            const float bvs = bias ? bias[col] : 0.f;
#pragma unroll
            for (int r = 0; r < 4; ++r) {
                float v = acc[i][j][r] + bvs;
                if (act == 1) v = 0.5f * v * (1.0f + erff(v * 0.70710678118f));
                else if (act == 2) v = 1.0f / (1.0f + __expf(-v));
                const size_t idx = (size_t)(rowb + r) * N + col;
                if (res) v += res[idx];
                if (outf32) ((float*)Cv)[idx] = v;
                else        ((u16*)Cv)[idx] = f2bits(v);
            }
        }
    }
}

// ---------- horizontal-fused wl+wg GEMM: gelu(A @ W^T + b), K=512, N=128, bf16 out ----
__global__ __launch_bounds__(256)
void gemm_wlg(const u16* __restrict__ L, const u16* __restrict__ G,
              const u16* __restrict__ WTl, const u16* __restrict__ WTg,
              const float* __restrict__ bl, const float* __restrict__ bg,
              u16* __restrict__ XL, u16* __restrict__ G2)
{
    constexpr int K = 512, N = 128;
    const u16* A; const u16* WT; const float* bias; u16* C;
    int bm, bn;
    const int blk = blockIdx.x;
    if (blk < 256) { A = L; WT = WTl; bias = bl; C = XL;
                     bm = (blk & 127) * 64; bn = (blk >> 7) * 64; }
    else           { const int b2 = blk - 256; A = G; WT = WTg; bias = bg; C = G2;
                     bm = (b2 & 31) * 64; bn = (b2 >> 5) * 64; }

    __shared__ u16 As[2][64*64];
    __shared__ u16 Bs[2][64*64];
    const int tid = threadIdx.x, wave = tid >> 6, lane = tid & 63;
    const int wm = (wave >> 1) * 32, wn = (wave & 1) * 32;
    const int lr = lane & 15, quad = lane >> 4;

    const int rowc = lane >> 3;
    const int kgs  = ((lane & 7) ^ (rowc & 7)) * 8;

    auto stage = [&](int buf, int k0) {
#pragma unroll
        for (int t = 0; t < 4; ++t) {
            const int c = wave*4 + t;
            if (c < 8) async16(&As[buf][c*512], A  + (size_t)(bm + c*8 + rowc) * K + k0 + kgs);
            else       async16(&Bs[buf][(c-8)*512], WT + (size_t)(bn + (c-8)*8 + rowc) * K + k0 + kgs);
        }
    };

    f32x4 acc[2][2] = {};
    stage(0, 0);
    __syncthreads();

    for (int ki = 0; ki < 8; ++ki) {
        const int cur = ki & 1;
        if (ki + 1 < 8) stage(cur ^ 1, (ki + 1) * 64);

        bf16x8 af[2][2], bv[2][2];
#pragma unroll
        for (int i = 0; i < 2; ++i) {
            const int rA = wm + i*16 + lr;
            const int sw = rA & 7;
#pragma unroll
            for (int kb = 0; kb < 2; ++kb)
                af[i][kb] = *(const bf16x8*)(As[cur] + rA*64 + (((kb*4 + quad) ^ sw) * 8));
        }
#pragma unroll
        for (int j = 0; j < 2; ++j) {
            const int rB = wn + j*16 + lr;
            const int sw = rB & 7;
#pragma unroll
            for (int kb = 0; kb < 2; ++kb)
                bv[j][kb] = *(const bf16x8*)(Bs[cur] + rB*64 + (((kb*4 + quad) ^ sw) * 8));
        }
#pragma unroll
        for (int i = 0; i < 2; ++i)
#pragma unroll
            for (int j = 0; j < 2; ++j)
#pragma unroll
                for (int kb = 0; kb < 2; ++kb)
                    acc[i][j] = __builtin_amdgcn_mfma_f32_16x16x32_bf16(
                        af[i][kb], bv[j][kb], acc[i][j], 0, 0, 0);
        __syncthreads();
    }

#pragma unroll
    for (int i = 0; i < 2; ++i) {
        const int rowb = bm + wm + i*16 + quad*4;
#pragma unroll
        for (int j = 0; j < 2; ++j) {
            const int col = bn + wn + j*16 + lr;
            const float bvs = bias[col];
#pragma unroll
            for (int r = 0; r < 4; ++r) {
                float v = acc[i][j][r] + bvs;
                v = 0.5f * v * (1.0f + erff(v * 0.70710678118f));
                C[(size_t)(rowb + r) * N + col] = f2bits(v);
            }
        }
    }
}

// ---------- MFMA flash attention, 4-way split-Q: one block per (b,p,h,qquarter) ----------
__global__ __launch_bounds__(256)
void attn_mfma(const u16* __restrict__ qkv, u16* __restrict__ out)
{
    __shared__ u16 Kt[64*72];
    __shared__ u16 Vt[64*72];
    __shared__ u16 Pw[4][16*72];
    const int tid = threadIdx.x;
    const int wave = tid >> 6, lane = tid & 63;
    const int lr = lane & 15, quad = lane >> 4;
    const int bp = blockIdx.x >> 5;          // (b,p)
    const int h  = (blockIdx.x >> 2) & 7;    // head
    const int qq = blockIdx.x & 3;           // query quarter
    const u16* base = qkv + (size_t)bp * NN * (3*DIM);
    const int qo = h*DHEAD, ko = DIM + h*DHEAD, vo = 2*DIM + h*DHEAD;
    const int m0 = qq*64 + wave*16;

    bf16x8 qf[2];
#pragma unroll
    for (int kb = 0; kb < 2; ++kb)
        qf[kb] = *(const bf16x8*)(base + (size_t)(m0 + lr)*(3*DIM) + qo + kb*32 + quad*8);

    f32x4 o[4] = {};
    float mrow[4], lrow[4];
#pragma unroll
    for (int r = 0; r < 4; ++r) { mrow[r] = -1e30f; lrow[r] = 0.f; }

    const int sr = tid >> 3, sc = tid & 7;

    for (int t = 0; t < 4; ++t) {
        __syncthreads();
#pragma unroll
        for (int half = 0; half < 2; ++half) {
            const int key = half*32 + sr;
            const u16* krow = base + (size_t)(t*64 + key)*(3*DIM);
            uint4 kv = *(const uint4*)(krow + ko + sc*8);
            *(uint4*)(Kt + key*72 + sc*8) = kv;
            uint4 vv = *(const uint4*)(krow + vo + sc*8);
            const int d0 = sc*8;
            Vt[(d0+0)*72 + key] = (u16)(vv.x & 0xffffu);
            Vt[(d0+1)*72 + key] = (u16)(vv.x >> 16);
            Vt[(d0+2)*72 + key] = (u16)(vv.y & 0xffffu);
            Vt[(d0+3)*72 + key] = (u16)(vv.y >> 16);
            Vt[(d0+4)*72 + key] = (u16)(vv.z & 0xffffu);
            Vt[(d0+5)*72 + key] = (u16)(vv.z >> 16);
            Vt[(d0+6)*72 + key] = (u16)(vv.w & 0xffffu);
            Vt[(d0+7)*72 + key] = (u16)(vv.w >> 16);
        }
        __syncthreads();

        f32x4 s[4] = {};
        bf16x8 kf[4][2];
#pragma unroll
        for (int j = 0; j < 4; ++j)
#pragma unroll
            for (int kb = 0; kb < 2; ++kb)
                kf[j][kb] = *(const bf16x8*)(Kt + (j*16 + lr)*72 + kb*32 + quad*8);
#pragma unroll
        for (int j = 0; j < 4; ++j)
#pragma unroll
            for (int kb = 0; kb < 2; ++kb)
                s[j] = __builtin_amdgcn_mfma_f32_16x16x32_bf16(
                    qf[kb], kf[j][kb], s[j], 0, 0, 0);

        float alpha[4];
#pragma unroll
        for (int r = 0; r < 4; ++r) {
#pragma unroll
            for (int j = 0; j < 4; ++j) s[j][r] *= 0.125f;
            float mt = fmaxf(fmaxf(s[0][r], s[1][r]), fmaxf(s[2][r], s[3][r]));
#pragma unroll
            for (int off = 1; off <= 8; off <<= 1) mt = fmaxf(mt, __shfl_xor(mt, off));
            const float mn = fmaxf(mrow[r], mt);
            alpha[r] = __expf(mrow[r] - mn);
            mrow[r] = mn;
            float ssum = 0.f;
#pragma unroll
            for (int j = 0; j < 4; ++j) {
                const float p = __expf(s[j][r] - mn);
                s[j][r] = p; ssum += p;
            }
#pragma unroll
            for (int off = 1; off <= 8; off <<= 1) ssum += __shfl_xor(ssum, off);
            lrow[r] = lrow[r]*alpha[r] + ssum;
        }

#pragma unroll
        for (int j = 0; j < 4; ++j)
#pragma unroll
            for (int r = 0; r < 4; ++r)
                Pw[wave][(quad*4 + r)*72 + j*16 + lr] = f2bits(s[j][r]);
        __syncthreads();

#pragma unroll
        for (int jd = 0; jd < 4; ++jd)
#pragma unroll
            for (int r = 0; r < 4; ++r)
                o[jd][r] *= alpha[r];

        bf16x8 af[2], bv[4][2];
#pragma unroll
        for (int kb = 0; kb < 2; ++kb)
            af[kb] = *(const bf16x8*)(Pw[wave] + lr*72 + kb*32 + quad*8);
#pragma unroll
        for (int jd = 0; jd < 4; ++jd)
#pragma unroll
            for (int kb = 0; kb < 2; ++kb)
                bv[jd][kb] = *(const bf16x8*)(Vt + (jd*16 + lr)*72 + kb*32 + quad*8);
#pragma unroll
        for (int jd = 0; jd < 4; ++jd)
#pragma unroll
            for (int kb = 0; kb < 2; ++kb)
                o[jd] = __builtin_amdgcn_mfma_f32_16x16x32_bf16(
                    af[kb], bv[jd][kb], o[jd], 0, 0, 0);
    }

#pragma unroll
    for (int r = 0; r < 4; ++r) {
        const float inv = 1.0f / lrow[r];
        const size_t rowg = (size_t)bp*NN + m0 + quad*4 + r;
#pragma unroll
        for (int jd = 0; jd < 4; ++jd)
            out[rowg*DIM + h*DHEAD + jd*16 + lr] = f2bits(o[jd][r] * inv);
    }
}

// ---------- LayerNorm over DIM=512, fp32 in, bf16 out; one wave per row; float4 ----------
__global__ __launch_bounds__(256)
void ln_kernel(const float* __restrict__ x, const float* __restrict__ g,
               const float* __restrict__ b, u16* __restrict__ y, int rows)
{
    const int wave = threadIdx.x >> 6, lane = threadIdx.x & 63;
    const int row = blockIdx.x * 4 + wave;
    if (row >= rows) return;
    const float4* xr = (const float4*)(x + (size_t)row * DIM);
    float4 v0 = xr[lane], v1 = xr[lane + 64];
    float s  = v0.x+v0.y+v0.z+v0.w + v1.x+v1.y+v1.z+v1.w;
    float s2 = v0.x*v0.x+v0.y*v0.y+v0.z*v0.z+v0.w*v0.w
             + v1.x*v1.x+v1.y*v1.y+v1.z*v1.z+v1.w*v1.w;
#pragma unroll
    for (int off = 32; off; off >>= 1) { s += __shfl_xor(s, off); s2 += __shfl_xor(s2, off); }
    const float mean = s * (1.f/512.f);
    const float var  = s2 * (1.f/512.f) - mean*mean;
    const float rstd = rsqrtf(var + 1e-5f);
    const float4* gp = (const float4*)g; const float4* bp = (const float4*)b;
    float4 g0 = gp[lane], g1 = gp[lane+64], b0 = bp[lane], b1 = bp[lane+64];
    ushort4 o0, o1;
    o0.x = f2bits((v0.x-mean)*rstd*g0.x + b0.x);
    o0.y = f2bits((v0.y-mean)*rstd*g0.y + b0.y);
    o0.z = f2bits((v0.z-mean)*rstd*g0.z + b0.z);
    o0.w = f2bits((v0.w-mean)*rstd*g0.w + b0.w);
    o1.x = f2bits((v1.x-mean)*rstd*g1.x + b1.x);
    o1.y = f2bits((v1.y-mean)*rstd*g1.y + b1.y);
    o1.z = f2bits((v1.z-mean)*rstd*g1.z + b1.z);
    o1.w = f2bits((v1.w-mean)*rstd*g1.w + b1.w);
    ushort4* yr = (ushort4*)(y + (size_t)row * DIM);
    yr[lane] = o0; yr[lane+64] = o1;
}

// ---------- fused BiAttn LN + mean over P: block=(b,n), wave p=0..3 ----------
__global__ __launch_bounds__(256)
void lnmean_kernel(const float* __restrict__ x, const float* __restrict__ g,
                   const float* __restrict__ b, u16* __restrict__ y,
                   u16* __restrict__ G)
{
    __shared__ float T[4][512];
    const int wave = threadIdx.x >> 6, lane = threadIdx.x & 63;
    const int bb = blockIdx.x >> 8, n = blockIdx.x & 255;
    const int row = (bb*PP + wave)*NN + n;
    const float4* xr = (const float4*)(x + (size_t)row * DIM);
    float4 v0 = xr[lane], v1 = xr[lane + 64];
    float s  = v0.x+v0.y+v0.z+v0.w + v1.x+v1.y+v1.z+v1.w;
    float s2 = v0.x*v0.x+v0.y*v0.y+v0.z*v0.z+v0.w*v0.w
             + v1.x*v1.x+v1.y*v1.y+v1.z*v1.z+v1.w*v1.w;
#pragma unroll
    for (int off = 32; off; off >>= 1) { s += __shfl_xor(s, off); s2 += __shfl_xor(s2, off); }
    const float mean = s * (1.f/512.f);
    const float var  = s2 * (1.f/512.f) - mean*mean;
    const float rstd = rsqrtf(var + 1e-5f);
    const float4* gp = (const float4*)g; const float4* bp = (const float4*)b;
    float4 g0 = gp[lane], g1 = gp[lane+64], b0 = bp[lane], b1 = bp[lane+64];
    float4 y0, y1;
    y0.x = (v0.x-mean)*rstd*g0.x + b0.x;
    y0.y = (v0.y-mean)*rstd*g0.y + b0.y;
    y0.z = (v0.z-mean)*rstd*g0.z + b0.z;
    y0.w = (v0.w-mean)*rstd*g0.w + b0.w;
    y1.x = (v1.x-mean)*rstd*g1.x + b1.x;
    y1.y = (v1.y-mean)*rstd*g1.y + b1.y;
    y1.z = (v1.z-mean)*rstd*g1.z + b1.z;
    y1.w = (v1.w-mean)*rstd*g1.w + b1.w;
    ushort4 o0, o1;
    o0.x = f2bits(y0.x); o0.y = f2bits(y0.y); o0.z = f2bits(y0.z); o0.w = f2bits(y0.w);
    o1.x = f2bits(y1.x); o1.y = f2bits(y1.y); o1.z = f2bits(y1.z); o1.w = f2bits(y1.w);
    ushort4* yr = (ushort4*)(y + (size_t)row * DIM);
    yr[lane] = o0; yr[lane+64] = o1;
    *(float4*)&T[wave][lane*4]       = y0;
    *(float4*)&T[wave][256 + lane*4] = y1;
    __syncthreads();
    const int d0 = threadIdx.x;   // 0..255, handles d0 and d0+256
    const float m0 = (T[0][d0]     + T[1][d0]     + T[2][d0]     + T[3][d0])     * 0.25f;
    const float m1 = (T[0][d0+256] + T[1][d0+256] + T[2][d0+256] + T[3][d0+256]) * 0.25f;
    u16* gr = G + ((size_t)bb*NN + n)*DIM;
    gr[d0]       = f2bits(m0);
    gr[d0 + 256] = f2bits(m1);
}

// ---------- fused s_attn + gating + residual + NEXT layer's ln1 ----------
__global__ __launch_bounds__(256)
void fuse2_kernel(const float4* __restrict__ xb, const float4* __restrict__ m1,
                  const u16* __restrict__ ca, const u16* __restrict__ xl,
                  const u16* __restrict__ xg, const float* __restrict__ wsv,
                  const float* __restrict__ bs, float4* __restrict__ xa,
                  const float* __restrict__ lng, const float* __restrict__ lnb,
                  u16* __restrict__ lnout)
{
    const int wave = threadIdx.x >> 6, lane = threadIdx.x & 63;
    const int row = blockIdx.x * 4 + wave;
    const int b = row >> 10, n = row & 255;
    const u16* xlr = xl + (size_t)row * RED;
    const u16* xgr = xg + ((size_t)b*NN + n) * RED;
    float s = bits2f(xlr[lane])    * wsv[lane]
            + bits2f(xlr[lane+64]) * wsv[lane+64]
            + bits2f(xgr[lane])    * wsv[RED+lane]
            + bits2f(xgr[lane+64]) * wsv[RED+64+lane];
#pragma unroll
    for (int off = 32; off; off >>= 1) s += __shfl_xor(s, off);
    s = 1.f / (1.f + __expf(-(s + bs[0])));
    const u16* car = ca + ((((size_t)b << 8) + n)*DIM);

    float4 o0, o1;
    {
        const size_t idx = (size_t)row*128 + lane;
        ushort4 cu = *(const ushort4*)(car + lane*4);
        float4 xv = xb[idx], mv = m1[idx];
        o0.x = xv.x + mv.x * bits2f(cu.x) * s;
        o0.y = xv.y + mv.y * bits2f(cu.y) * s;
        o0.z = xv.z + mv.z * bits2f(cu.z) * s;
        o0.w = xv.w + mv.w * bits2f(cu.w) * s;
        xa[idx] = o0;
    }
    {
        const size_t idx = (size_t)row*128 + lane + 64;
        ushort4 cu = *(const ushort4*)(car + (lane + 64)*4);
        float4 xv = xb[idx], mv = m1[idx];
        o1.x = xv.x + mv.x * bits2f(cu.x) * s;
        o1.y = xv.y + mv.y * bits2f(cu.y) * s;
        o1.z = xv.z + mv.z * bits2f(cu.z) * s;
        o1.w = xv.w + mv.w * bits2f(cu.w) * s;
        xa[idx] = o1;
    }

    if (lnout) {   // next layer's ln1, computed from the row already in registers
        float t  = o0.x+o0.y+o0.z+o0.w + o1.x+o1.y+o1.z+o1.w;
        float t2 = o0.x*o0.x+o0.y*o0.y+o0.z*o0.z+o0.w*o0.w
                 + o1.x*o1.x+o1.y*o1.y+o1.z*o1.z+o1.w*o1.w;
#pragma unroll
        for (int off = 32; off; off >>= 1) { t += __shfl_xor(t, off); t2 += __shfl_xor(t2, off); }
        const float mean = t * (1.f/512.f);
        const float var  = t2 * (1.f/512.f) - mean*mean;
        const float rstd = rsqrtf(var + 1e-5f);
        const float4* gp = (const float4*)lng; const float4* bp = (const float4*)lnb;
        float4 g0 = gp[lane], g1 = gp[lane+64], b0 = bp[lane], b1 = bp[lane+64];
        ushort4 q0, q1;
        q0.x = f2bits((o0.x-mean)*rstd*g0.x + b0.x);
        q0.y = f2bits((o0.y-mean)*rstd*g0.y + b0.y);
        q0.z = f2bits((o0.z-mean)*rstd*g0.z + b0.z);
        q0.w = f2bits((o0.w-mean)*rstd*g0.w + b0.w);
        q1.x = f2bits((o1.x-mean)*rstd*g1.x + b1.x);
        q1.y = f2bits((o1.y-mean)*rstd*g1.y + b1.y);
        q1.z = f2bits((o1.z-mean)*rstd*g1.z + b1.z);
        q1.w = f2bits((o1.w-mean)*rstd*g1.w + b1.w);
        ushort4* yr = (ushort4*)(lnout + (size_t)row * DIM);
        yr[lane] = q0; yr[lane+64] = q1;
    }
}

// ---------- host launch ----------
extern "C" void kernel_launch(void* const* d_in, const int* in_sizes, int n_in,
                              void* d_out, int out_size, void* d_ws, size_t ws_size,
                              hipStream_t stream)
{
    const float* x_in  = (const float*)d_in[0];
    const float* ln1_g = (const float*)d_in[1];
    const float* ln1_b = (const float*)d_in[2];
    const float* w_qkv = (const float*)d_in[3];
    const float* w_o   = (const float*)d_in[4];
    const float* b_o   = (const float*)d_in[5];
    const float* ln2_g = (const float*)d_in[6];
    const float* ln2_b = (const float*)d_in[7];
    const float* w1    = (const float*)d_in[8];
    const float* b1    = (const float*)d_in[9];
    const float* w2    = (const float*)d_in[10];
    const float* b2    = (const float*)d_in[11];
    const float* bn_g  = (const float*)d_in[12];
    const float* bn_b  = (const float*)d_in[13];
    const float* wg    = (const float*)d_in[14];
    const float* bg    = (const float*)d_in[15];
    const float* wl    = (const float*)d_in[16];
    const float* bl    = (const float*)d_in[17];
    const float* wc    = (const float*)d_in[18];
    const float* bc    = (const float*)d_in[19];
    const float* wsw   = (const float*)d_in[20];
    const float* bsb   = (const float*)d_in[21];

    char* ws = (char*)d_ws;
    auto alloc = [&](size_t bytes) {
        char* p = ws;
        ws += (bytes + 255) & ~(size_t)255;
        return p;
    };
    float* XA = (float*)alloc(XELEMS * 4);
    float* XB = (float*)alloc(XELEMS * 4);
    float* M1 = (float*)alloc(XELEMS * 4);
    u16*   L  = (u16*)  alloc(XELEMS * 2);
    u16*   Q  = (u16*)  alloc((size_t)ROWS * 3*DIM * 2);
    u16*   H  = (u16*)  alloc((size_t)ROWS * MLPD * 2);
    u16*   G  = (u16*)  alloc((size_t)BB*NN*DIM * 2);
    u16*   G2 = (u16*)  alloc((size_t)BB*NN*RED * 2);
    u16*   XL = (u16*)  alloc((size_t)ROWS*RED * 2);
    u16*   CA = (u16*)  alloc((size_t)BB*NN*DIM * 2);
    // all-layer transposed bf16 weights
    u16* WTqkv = (u16*)alloc((size_t)DEPTH*DIM*3*DIM * 2);
    u16* WTo   = (u16*)alloc((size_t)DEPTH*DIM*DIM * 2);
    u16* WT1   = (u16*)alloc((size_t)DEPTH*DIM*MLPD * 2);
    u16* WT2   = (u16*)alloc((size_t)DEPTH*MLPD*DIM * 2);
    u16* WTl   = (u16*)alloc((size_t)DEPTH*DIM*RED * 2);
    u16* WTg   = (u16*)alloc((size_t)DEPTH*DIM*RED * 2);
    u16* WTc   = (u16*)alloc((size_t)DEPTH*RED*DIM * 2);

    // ---- all weight transposes in ONE launch (segmented grid) ----
    wtrans_fused<<<dim3(3264, 1, DEPTH), 256, 0, stream>>>(
        w_qkv, WTqkv, w_o, WTo, w1, WT1, w2, WT2, wl, WTl, wg, WTg, wc, WTc);

    // layer-0 attention LN (reads the external input); layers 1-3 get L from fuse2
    ln_kernel<<<ROWS/4, 256, 0, stream>>>(x_in, ln1_g, ln1_b, L, ROWS);

    for (int l = 0; l < DEPTH; ++l) {
        const float* Xres = l ? (const float*)XA : x_in;
        // ---- attention block ----
        gemm_db<64,64,64,2,2><<<dim3(128,24), 256, 0, stream>>>(
            L, WTqkv + (size_t)l*DIM*3*DIM, nullptr, nullptr, Q, ROWS, 3*DIM, DIM, 0, 0);
        attn_mfma<<<BB*PP*HEADS*4, 256, 0, stream>>>(Q, L);
        gemm_db<64,64,64,2,2><<<dim3(128,8), 256, 0, stream>>>(
            L, WTo + (size_t)l*DIM*DIM, b_o + l*DIM, Xres, XB, ROWS, DIM, DIM, 0, 1);

        // ---- MLP ----
        ln_kernel<<<ROWS/4, 256, 0, stream>>>(XB, ln2_g + l*DIM, ln2_b + l*DIM, Q, ROWS);
        gemm_8ph<<<dim3(32,8), 512, 0, stream>>>(
            Q, WT1 + (size_t)l*DIM*MLPD, b1 + l*MLPD, nullptr, H, ROWS, MLPD, DIM, 1, 0);
        gemm_db<64,64,64,2,2><<<dim3(128,8), 256, 0, stream>>>(
            H, WT2 + (size_t)l*MLPD*DIM, b2 + l*DIM, nullptr, M1, ROWS, DIM, MLPD, 0, 1);

        // ---- BiAttn ----
        lnmean_kernel<<<BB*NN, 256, 0, stream>>>(M1, bn_g + l*DIM, bn_b + l*DIM, L, G);
        gemm_wlg<<<320, 256, 0, stream>>>(L, G, WTl + (size_t)l*DIM*RED,
                                          WTg + (size_t)l*DIM*RED,
                                          bl + l*RED, bg + l*RED, XL, G2);
        gemm_db<64,64,64,2,2><<<dim3(32,8), 256, 0, stream>>>(
            G2, WTc + (size_t)l*RED*DIM, bc + l*DIM, nullptr, CA, BB*NN, DIM, RED, 2, 0);
        // fused s_attn + gating + residual (+ next layer's ln1 for l<3)
        const int last = (l == DEPTH-1);
        fuse2_kernel<<<ROWS/4, 256, 0, stream>>>(
            (const float4*)XB, (const float4*)M1, CA, XL, G2,
            wsw + (size_t)l*2*RED, bsb + l,
            last ? (float4*)d_out : (float4*)XA,
            ln1_g + (l+1)*DIM, ln1_b + (l+1)*DIM,
            last ? nullptr : L);
    }
}

// Round 12
// 816.069 us; speedup vs baseline: 1.0567x; 1.0567x over previous
//
#include <hip/hip_runtime.h>
#include <hip/hip_bf16.h>
#include <math.h>

typedef __hip_bfloat16 bf16;
typedef unsigned short u16;
typedef __bf16 bf16x8 __attribute__((ext_vector_type(8)));
typedef float f32x4 __attribute__((ext_vector_type(4)));

// ---------- helpers ----------
__device__ __forceinline__ float b2f(bf16 v) { return __bfloat162float(v); }
__device__ __forceinline__ bf16 f2b(float v) { return __float2bfloat16(v); }
__device__ __forceinline__ float bits2f(unsigned int u) {
    union { unsigned int i; float f; } w; w.i = u << 16; return w.f;
}
__device__ __forceinline__ u16 f2bits(float v) {
    union { bf16 h; u16 u; } w; w.h = __float2bfloat16(v); return w.u;
}
__device__ __forceinline__ void async16(void* lds, const void* g) {
    __builtin_amdgcn_global_load_lds(
        (const __attribute__((address_space(1))) unsigned int*)g,
        (__attribute__((address_space(3))) unsigned int*)lds, 16, 0, 0);
}

#define DEPTH 4
#define HEADS 8
#define DHEAD 64
#define DIM 512
#define MLPD 2048
#define RED 128
#define BB 8
#define PP 4
#define NN 256
#define ROWS (BB*PP*NN)          // 8192 tokens
#define XELEMS ((size_t)ROWS*DIM) // 4194304

// ---------- fused batched weight transpose+cast, ALL 7 weights in one launch ----------
__global__ __launch_bounds__(256)
void wtrans_fused(const float* __restrict__ Wqkv, u16* __restrict__ Tqkv,
                  const float* __restrict__ Wo,   u16* __restrict__ To,
                  const float* __restrict__ W1,   u16* __restrict__ T1,
                  const float* __restrict__ W2,   u16* __restrict__ T2,
                  const float* __restrict__ Wl,   u16* __restrict__ Tl,
                  const float* __restrict__ Wg,   u16* __restrict__ Tg,
                  const float* __restrict__ Wc,   u16* __restrict__ Tc)
{
    __shared__ float T[32][33];
    const int x = blockIdx.x, l = blockIdx.z;
    const float* W; u16* WT; int K, N, nx, local;
    if      (x < 768)  { W=Wqkv; WT=Tqkv; K=512;  N=1536; nx=48; local=x; }
    else if (x < 1024) { W=Wo;   WT=To;   K=512;  N=512;  nx=16; local=x-768; }
    else if (x < 2048) { W=W1;   WT=T1;   K=512;  N=2048; nx=64; local=x-1024; }
    else if (x < 3072) { W=W2;   WT=T2;   K=2048; N=512;  nx=16; local=x-2048; }
    else if (x < 3136) { W=Wl;   WT=Tl;   K=512;  N=128;  nx=4;  local=x-3072; }
    else if (x < 3200) { W=Wg;   WT=Tg;   K=512;  N=128;  nx=4;  local=x-3136; }
    else               { W=Wc;   WT=Tc;   K=128;  N=512;  nx=16; local=x-3200; }
    W  += (size_t)l * K * N;
    WT += (size_t)l * N * K;
    const int n0 = (local % nx) * 32, k0 = (local / nx) * 32;
    const int tx = threadIdx.x & 31, ty = threadIdx.x >> 5;
#pragma unroll
    for (int r = 0; r < 4; ++r)
        T[ty + r*8][tx] = W[(size_t)(k0 + ty + r*8) * N + n0 + tx];
    __syncthreads();
#pragma unroll
    for (int r = 0; r < 4; ++r)
        WT[(size_t)(n0 + ty + r*8) * K + k0 + tx] = f2bits(T[tx][ty + r*8]);
}

// ---------- double-buffered MFMA GEMM (2-phase, full drain): C = act(A @ WT^T + bias) [+res]
template<int BM, int BN, int BK, int WROWS, int WCOLS>
__global__ __launch_bounds__(256)
void gemm_db(const u16* __restrict__ A, const u16* __restrict__ WT,
             const float* __restrict__ bias, const float* __restrict__ res,
             void* __restrict__ Cv, int M, int N, int K, int act, int outf32)
{
    constexpr int KG  = BK/8;        // 16B k-groups per row
    constexpr int RPC = 512/BK;      // rows per 1KB staging chunk
    constexpr int NCA = BM*BK/512;   // A chunks
    constexpr int NCB = BN*BK/512;   // B chunks
    constexpr int CPT = (NCA+NCB)/4; // chunks per wave
    constexpr int WM = BM/WROWS, WN = BN/WCOLS;
    constexpr int AM = WM/16, AN = WN/16, KB = BK/32;

    __shared__ u16 As[2][BM*BK];
    __shared__ u16 Bs[2][BN*BK];
    const int tid = threadIdx.x, wave = tid >> 6, lane = tid & 63;
    const int bm = blockIdx.x * BM;
    const int bn = blockIdx.y * BN;
    const int wm = (wave / WCOLS) * WM, wn = (wave % WCOLS) * WN;
    const int lr = lane & 15, quad = lane >> 4;

    const int rowc = lane / KG;
    const int kgs  = ((lane & (KG-1)) ^ (KG == 4 ? ((rowc >> 1) & 3) : (rowc & 7))) * 8;

    auto stage = [&](int buf, int k0) {
#pragma unroll
        for (int t = 0; t < CPT; ++t) {
            const int c = wave*CPT + t;
            if (c < NCA)
                async16(&As[buf][c*512], A  + (size_t)(bm + c*RPC + rowc) * K + k0 + kgs);
            else
                async16(&Bs[buf][(c-NCA)*512], WT + (size_t)(bn + (c-NCA)*RPC + rowc) * K + k0 + kgs);
        }
    };

    f32x4 acc[AM][AN] = {};

    stage(0, 0);
    __syncthreads();

    const int NK = K / BK;
    for (int ki = 0; ki < NK; ++ki) {
        const int cur = ki & 1;
        if (ki + 1 < NK) stage(cur ^ 1, (ki + 1) * BK);

        bf16x8 af[AM][KB], bv[AN][KB];
#pragma unroll
        for (int i = 0; i < AM; ++i) {
            const int rA = wm + i*16 + lr;
            const int sw = (KG == 4 ? (((rA & 15) >> 1) & 3) : (rA & 7));
#pragma unroll
            for (int kb = 0; kb < KB; ++kb)
                af[i][kb] = *(const bf16x8*)(As[cur] + rA*BK + (((kb*4 + quad) ^ sw) * 8));
        }
#pragma unroll
        for (int j = 0; j < AN; ++j) {
            const int rB = wn + j*16 + lr;
            const int sw = (KG == 4 ? (((rB & 15) >> 1) & 3) : (rB & 7));
#pragma unroll
            for (int kb = 0; kb < KB; ++kb)
                bv[j][kb] = *(const bf16x8*)(Bs[cur] + rB*BK + (((kb*4 + quad) ^ sw) * 8));
        }
#pragma unroll
        for (int i = 0; i < AM; ++i)
#pragma unroll
            for (int j = 0; j < AN; ++j)
#pragma unroll
                for (int kb = 0; kb < KB; ++kb)
                    acc[i][j] = __builtin_amdgcn_mfma_f32_16x16x32_bf16(
                        af[i][kb], bv[j][kb], acc[i][j], 0, 0, 0);
        __syncthreads();
    }

#pragma unroll
    for (int i = 0; i < AM; ++i) {
        const int rowb = bm + wm + i*16 + quad*4;
#pragma unroll
        for (int j = 0; j < AN; ++j) {
            const int col = bn + wn + j*16 + lr;
            const float bvs = bias ? bias[col] : 0.f;
#pragma unroll
            for (int r = 0; r < 4; ++r) {
                float v = acc[i][j][r] + bvs;
                if (act == 1) v = 0.5f * v * (1.0f + erff(v * 0.70710678118f));
                else if (act == 2) v = 1.0f / (1.0f + __expf(-v));
                const size_t idx = (size_t)(rowb + r) * N + col;
                if (res) v += res[idx];
                if (outf32) ((float*)Cv)[idx] = v;
                else        ((u16*)Cv)[idx] = f2bits(v);
            }
        }
    }
}

// ---------- counted-barrier 2-phase GEMM: same as gemm_db but raw s_barrier +
// counted vmcnt(CPT) so the previous tile's loads stay in flight for a full
// iteration instead of being drained right after issue (gemm_p2 schedule,
// correctness-verified at 256^2 in round 3; only the wait count differs).
template<int BM, int BN, int BK, int WROWS, int WCOLS>
__global__ __launch_bounds__(256)
void gemm_cb(const u16* __restrict__ A, const u16* __restrict__ WT,
             const float* __restrict__ bias, const float* __restrict__ res,
             void* __restrict__ Cv, int M, int N, int K, int act, int outf32)
{
    constexpr int KG  = BK/8;
    constexpr int RPC = 512/BK;
    constexpr int NCA = BM*BK/512;
    constexpr int NCB = BN*BK/512;
    constexpr int CPT = (NCA+NCB)/4;
    constexpr int WM = BM/WROWS, WN = BN/WCOLS;
    constexpr int AM = WM/16, AN = WN/16, KB = BK/32;

    __shared__ u16 As[2][BM*BK];
    __shared__ u16 Bs[2][BN*BK];
    const int tid = threadIdx.x, wave = tid >> 6, lane = tid & 63;
    const int bm = blockIdx.x * BM;
    const int bn = blockIdx.y * BN;
    const int wm = (wave / WCOLS) * WM, wn = (wave % WCOLS) * WN;
    const int lr = lane & 15, quad = lane >> 4;

    const int rowc = lane / KG;
    const int kgs  = ((lane & (KG-1)) ^ (KG == 4 ? ((rowc >> 1) & 3) : (rowc & 7))) * 8;

    auto stage = [&](int buf, int k0) {
#pragma unroll
        for (int t = 0; t < CPT; ++t) {
            const int c = wave*CPT + t;
            if (c < NCA)
                async16(&As[buf][c*512], A  + (size_t)(bm + c*RPC + rowc) * K + k0 + kgs);
            else
                async16(&Bs[buf][(c-NCA)*512], WT + (size_t)(bn + (c-NCA)*RPC + rowc) * K + k0 + kgs);
        }
    };

    f32x4 acc[AM][AN] = {};

    stage(0, 0);
    const int NK = K / BK;
    for (int ki = 0; ki < NK; ++ki) {
        const int cur = ki & 1;
        if (ki + 1 < NK) {
            stage(cur ^ 1, (ki + 1) * BK);   // issue next tile FIRST
            // counted wait: retire only tile ki's CPT loads; next tile's stay in flight
            if constexpr (CPT == 2)      asm volatile("s_waitcnt vmcnt(2)" ::: "memory");
            else if constexpr (CPT == 4) asm volatile("s_waitcnt vmcnt(4)" ::: "memory");
            else                          asm volatile("s_waitcnt vmcnt(0)" ::: "memory");
        } else {
            asm volatile("s_waitcnt vmcnt(0)" ::: "memory");
        }
        __builtin_amdgcn_s_barrier();        // all waves past their vmcnt -> tile ki ready

        bf16x8 af[AM][KB], bv[AN][KB];
#pragma unroll
        for (int i = 0; i < AM; ++i) {
            const int rA = wm + i*16 + lr;
            const int sw = (KG == 4 ? (((rA & 15) >> 1) & 3) : (rA & 7));
#pragma unroll
            for (int kb = 0; kb < KB; ++kb)
                af[i][kb] = *(const bf16x8*)(As[cur] + rA*BK + (((kb*4 + quad) ^ sw) * 8));
        }
#pragma unroll
        for (int j = 0; j < AN; ++j) {
            const int rB = wn + j*16 + lr;
            const int sw = (KG == 4 ? (((rB & 15) >> 1) & 3) : (rB & 7));
#pragma unroll
            for (int kb = 0; kb < KB; ++kb)
                bv[j][kb] = *(const bf16x8*)(Bs[cur] + rB*BK + (((kb*4 + quad) ^ sw) * 8));
        }
#pragma unroll
        for (int i = 0; i < AM; ++i)
#pragma unroll
            for (int j = 0; j < AN; ++j)
#pragma unroll
                for (int kb = 0; kb < KB; ++kb)
                    acc[i][j] = __builtin_amdgcn_mfma_f32_16x16x32_bf16(
                        af[i][kb], bv[j][kb], acc[i][j], 0, 0, 0);
        __builtin_amdgcn_s_barrier();        // reads consumed into regs; cur may be overwritten
    }

#pragma unroll
    for (int i = 0; i < AM; ++i) {
        const int rowb = bm + wm + i*16 + quad*4;
#pragma unroll
        for (int j = 0; j < AN; ++j) {
            const int col = bn + wn + j*16 + lr;
            const float bvs = bias ? bias[col] : 0.f;
#pragma unroll
            for (int r = 0; r < 4; ++r) {
                float v = acc[i][j][r] + bvs;
                if (act == 1) v = 0.5f * v * (1.0f + erff(v * 0.70710678118f));
                else if (act == 2) v = 1.0f / (1.0f + __expf(-v));
                const size_t idx = (size_t)(rowb + r) * N + col;
                if (res) v += res[idx];
                if (outf32) ((float*)Cv)[idx] = v;
                else        ((u16*)Cv)[idx] = f2bits(v);
            }
        }
    }
}

// ---------- horizontal-fused wl+wg GEMM: gelu(A @ W^T + b), K=512, N=128, bf16 out ----
__global__ __launch_bounds__(256)
void gemm_wlg(const u16* __restrict__ L, const u16* __restrict__ G,
              const u16* __restrict__ WTl, const u16* __restrict__ WTg,
              const float* __restrict__ bl, const float* __restrict__ bg,
              u16* __restrict__ XL, u16* __restrict__ G2)
{
    constexpr int K = 512, N = 128;
    const u16* A; const u16* WT; const float* bias; u16* C;
    int bm, bn;
    const int blk = blockIdx.x;
    if (blk < 256) { A = L; WT = WTl; bias = bl; C = XL;
                     bm = (blk & 127) * 64; bn = (blk >> 7) * 64; }
    else           { const int b2 = blk - 256; A = G; WT = WTg; bias = bg; C = G2;
                     bm = (b2 & 31) * 64; bn = (b2 >> 5) * 64; }

    __shared__ u16 As[2][64*64];
    __shared__ u16 Bs[2][64*64];
    const int tid = threadIdx.x, wave = tid >> 6, lane = tid & 63;
    const int wm = (wave >> 1) * 32, wn = (wave & 1) * 32;
    const int lr = lane & 15, quad = lane >> 4;

    const int rowc = lane >> 3;
    const int kgs  = ((lane & 7) ^ (rowc & 7)) * 8;

    auto stage = [&](int buf, int k0) {
#pragma unroll
        for (int t = 0; t < 4; ++t) {
            const int c = wave*4 + t;
            if (c < 8) async16(&As[buf][c*512], A  + (size_t)(bm + c*8 + rowc) * K + k0 + kgs);
            else       async16(&Bs[buf][(c-8)*512], WT + (size_t)(bn + (c-8)*8 + rowc) * K + k0 + kgs);
        }
    };

    f32x4 acc[2][2] = {};
    stage(0, 0);
    __syncthreads();

    for (int ki = 0; ki < 8; ++ki) {
        const int cur = ki & 1;
        if (ki + 1 < 8) stage(cur ^ 1, (ki + 1) * 64);

        bf16x8 af[2][2], bv[2][2];
#pragma unroll
        for (int i = 0; i < 2; ++i) {
            const int rA = wm + i*16 + lr;
            const int sw = rA & 7;
#pragma unroll
            for (int kb = 0; kb < 2; ++kb)
                af[i][kb] = *(const bf16x8*)(As[cur] + rA*64 + (((kb*4 + quad) ^ sw) * 8));
        }
#pragma unroll
        for (int j = 0; j < 2; ++j) {
            const int rB = wn + j*16 + lr;
            const int sw = rB & 7;
#pragma unroll
            for (int kb = 0; kb < 2; ++kb)
                bv[j][kb] = *(const bf16x8*)(Bs[cur] + rB*64 + (((kb*4 + quad) ^ sw) * 8));
        }
#pragma unroll
        for (int i = 0; i < 2; ++i)
#pragma unroll
            for (int j = 0; j < 2; ++j)
#pragma unroll
                for (int kb = 0; kb < 2; ++kb)
                    acc[i][j] = __builtin_amdgcn_mfma_f32_16x16x32_bf16(
                        af[i][kb], bv[j][kb], acc[i][j], 0, 0, 0);
        __syncthreads();
    }

#pragma unroll
    for (int i = 0; i < 2; ++i) {
        const int rowb = bm + wm + i*16 + quad*4;
#pragma unroll
        for (int j = 0; j < 2; ++j) {
            const int col = bn + wn + j*16 + lr;
            const float bvs = bias[col];
#pragma unroll
            for (int r = 0; r < 4; ++r) {
                float v = acc[i][j][r] + bvs;
                v = 0.5f * v * (1.0f + erff(v * 0.70710678118f));
                C[(size_t)(rowb + r) * N + col] = f2bits(v);
            }
        }
    }
}

// ---------- MFMA flash attention, 4-way split-Q: one block per (b,p,h,qquarter) ----------
__global__ __launch_bounds__(256)
void attn_mfma(const u16* __restrict__ qkv, u16* __restrict__ out)
{
    __shared__ u16 Kt[64*72];
    __shared__ u16 Vt[64*72];
    __shared__ u16 Pw[4][16*72];
    const int tid = threadIdx.x;
    const int wave = tid >> 6, lane = tid & 63;
    const int lr = lane & 15, quad = lane >> 4;
    const int bp = blockIdx.x >> 5;          // (b,p)
    const int h  = (blockIdx.x >> 2) & 7;    // head
    const int qq = blockIdx.x & 3;           // query quarter
    const u16* base = qkv + (size_t)bp * NN * (3*DIM);
    const int qo = h*DHEAD, ko = DIM + h*DHEAD, vo = 2*DIM + h*DHEAD;
    const int m0 = qq*64 + wave*16;

    bf16x8 qf[2];
#pragma unroll
    for (int kb = 0; kb < 2; ++kb)
        qf[kb] = *(const bf16x8*)(base + (size_t)(m0 + lr)*(3*DIM) + qo + kb*32 + quad*8);

    f32x4 o[4] = {};
    float mrow[4], lrow[4];
#pragma unroll
    for (int r = 0; r < 4; ++r) { mrow[r] = -1e30f; lrow[r] = 0.f; }

    const int sr = tid >> 3, sc = tid & 7;

    for (int t = 0; t < 4; ++t) {
        __syncthreads();
#pragma unroll
        for (int half = 0; half < 2; ++half) {
            const int key = half*32 + sr;
            const u16* krow = base + (size_t)(t*64 + key)*(3*DIM);
            uint4 kv = *(const uint4*)(krow + ko + sc*8);
            *(uint4*)(Kt + key*72 + sc*8) = kv;
            uint4 vv = *(const uint4*)(krow + vo + sc*8);
            const int d0 = sc*8;
            Vt[(d0+0)*72 + key] = (u16)(vv.x & 0xffffu);
            Vt[(d0+1)*72 + key] = (u16)(vv.x >> 16);
            Vt[(d0+2)*72 + key] = (u16)(vv.y & 0xffffu);
            Vt[(d0+3)*72 + key] = (u16)(vv.y >> 16);
            Vt[(d0+4)*72 + key] = (u16)(vv.z & 0xffffu);
            Vt[(d0+5)*72 + key] = (u16)(vv.z >> 16);
            Vt[(d0+6)*72 + key] = (u16)(vv.w & 0xffffu);
            Vt[(d0+7)*72 + key] = (u16)(vv.w >> 16);
        }
        __syncthreads();

        f32x4 s[4] = {};
        bf16x8 kf[4][2];
#pragma unroll
        for (int j = 0; j < 4; ++j)
#pragma unroll
            for (int kb = 0; kb < 2; ++kb)
                kf[j][kb] = *(const bf16x8*)(Kt + (j*16 + lr)*72 + kb*32 + quad*8);
#pragma unroll
        for (int j = 0; j < 4; ++j)
#pragma unroll
            for (int kb = 0; kb < 2; ++kb)
                s[j] = __builtin_amdgcn_mfma_f32_16x16x32_bf16(
                    qf[kb], kf[j][kb], s[j], 0, 0, 0);

        float alpha[4];
#pragma unroll
        for (int r = 0; r < 4; ++r) {
#pragma unroll
            for (int j = 0; j < 4; ++j) s[j][r] *= 0.125f;
            float mt = fmaxf(fmaxf(s[0][r], s[1][r]), fmaxf(s[2][r], s[3][r]));
#pragma unroll
            for (int off = 1; off <= 8; off <<= 1) mt = fmaxf(mt, __shfl_xor(mt, off));
            const float mn = fmaxf(mrow[r], mt);
            alpha[r] = __expf(mrow[r] - mn);
            mrow[r] = mn;
            float ssum = 0.f;
#pragma unroll
            for (int j = 0; j < 4; ++j) {
                const float p = __expf(s[j][r] - mn);
                s[j][r] = p; ssum += p;
            }
#pragma unroll
            for (int off = 1; off <= 8; off <<= 1) ssum += __shfl_xor(ssum, off);
            lrow[r] = lrow[r]*alpha[r] + ssum;
        }

#pragma unroll
        for (int j = 0; j < 4; ++j)
#pragma unroll
            for (int r = 0; r < 4; ++r)
                Pw[wave][(quad*4 + r)*72 + j*16 + lr] = f2bits(s[j][r]);
        __syncthreads();

#pragma unroll
        for (int jd = 0; jd < 4; ++jd)
#pragma unroll
            for (int r = 0; r < 4; ++r)
                o[jd][r] *= alpha[r];

        bf16x8 af[2], bv[4][2];
#pragma unroll
        for (int kb = 0; kb < 2; ++kb)
            af[kb] = *(const bf16x8*)(Pw[wave] + lr*72 + kb*32 + quad*8);
#pragma unroll
        for (int jd = 0; jd < 4; ++jd)
#pragma unroll
            for (int kb = 0; kb < 2; ++kb)
                bv[jd][kb] = *(const bf16x8*)(Vt + (jd*16 + lr)*72 + kb*32 + quad*8);
#pragma unroll
        for (int jd = 0; jd < 4; ++jd)
#pragma unroll
            for (int kb = 0; kb < 2; ++kb)
                o[jd] = __builtin_amdgcn_mfma_f32_16x16x32_bf16(
                    af[kb], bv[jd][kb], o[jd], 0, 0, 0);
    }

#pragma unroll
    for (int r = 0; r < 4; ++r) {
        const float inv = 1.0f / lrow[r];
        const size_t rowg = (size_t)bp*NN + m0 + quad*4 + r;
#pragma unroll
        for (int jd = 0; jd < 4; ++jd)
            out[rowg*DIM + h*DHEAD + jd*16 + lr] = f2bits(o[jd][r] * inv);
    }
}

// ---------- LayerNorm over DIM=512, fp32 in, bf16 out; one wave per row; float4 ----------
__global__ __launch_bounds__(256)
void ln_kernel(const float* __restrict__ x, const float* __restrict__ g,
               const float* __restrict__ b, u16* __restrict__ y, int rows)
{
    const int wave = threadIdx.x >> 6, lane = threadIdx.x & 63;
    const int row = blockIdx.x * 4 + wave;
    if (row >= rows) return;
    const float4* xr = (const float4*)(x + (size_t)row * DIM);
    float4 v0 = xr[lane], v1 = xr[lane + 64];
    float s  = v0.x+v0.y+v0.z+v0.w + v1.x+v1.y+v1.z+v1.w;
    float s2 = v0.x*v0.x+v0.y*v0.y+v0.z*v0.z+v0.w*v0.w
             + v1.x*v1.x+v1.y*v1.y+v1.z*v1.z+v1.w*v1.w;
#pragma unroll
    for (int off = 32; off; off >>= 1) { s += __shfl_xor(s, off); s2 += __shfl_xor(s2, off); }
    const float mean = s * (1.f/512.f);
    const float var  = s2 * (1.f/512.f) - mean*mean;
    const float rstd = rsqrtf(var + 1e-5f);
    const float4* gp = (const float4*)g; const float4* bp = (const float4*)b;
    float4 g0 = gp[lane], g1 = gp[lane+64], b0 = bp[lane], b1 = bp[lane+64];
    ushort4 o0, o1;
    o0.x = f2bits((v0.x-mean)*rstd*g0.x + b0.x);
    o0.y = f2bits((v0.y-mean)*rstd*g0.y + b0.y);
    o0.z = f2bits((v0.z-mean)*rstd*g0.z + b0.z);
    o0.w = f2bits((v0.w-mean)*rstd*g0.w + b0.w);
    o1.x = f2bits((v1.x-mean)*rstd*g1.x + b1.x);
    o1.y = f2bits((v1.y-mean)*rstd*g1.y + b1.y);
    o1.z = f2bits((v1.z-mean)*rstd*g1.z + b1.z);
    o1.w = f2bits((v1.w-mean)*rstd*g1.w + b1.w);
    ushort4* yr = (ushort4*)(y + (size_t)row * DIM);
    yr[lane] = o0; yr[lane+64] = o1;
}

// ---------- fused BiAttn LN + mean over P: block=(b,n), wave p=0..3 ----------
__global__ __launch_bounds__(256)
void lnmean_kernel(const float* __restrict__ x, const float* __restrict__ g,
                   const float* __restrict__ b, u16* __restrict__ y,
                   u16* __restrict__ G)
{
    __shared__ float T[4][512];
    const int wave = threadIdx.x >> 6, lane = threadIdx.x & 63;
    const int bb = blockIdx.x >> 8, n = blockIdx.x & 255;
    const int row = (bb*PP + wave)*NN + n;
    const float4* xr = (const float4*)(x + (size_t)row * DIM);
    float4 v0 = xr[lane], v1 = xr[lane + 64];
    float s  = v0.x+v0.y+v0.z+v0.w + v1.x+v1.y+v1.z+v1.w;
    float s2 = v0.x*v0.x+v0.y*v0.y+v0.z*v0.z+v0.w*v0.w
             + v1.x*v1.x+v1.y*v1.y+v1.z*v1.z+v1.w*v1.w;
#pragma unroll
    for (int off = 32; off; off >>= 1) { s += __shfl_xor(s, off); s2 += __shfl_xor(s2, off); }
    const float mean = s * (1.f/512.f);
    const float var  = s2 * (1.f/512.f) - mean*mean;
    const float rstd = rsqrtf(var + 1e-5f);
    const float4* gp = (const float4*)g; const float4* bp = (const float4*)b;
    float4 g0 = gp[lane], g1 = gp[lane+64], b0 = bp[lane], b1 = bp[lane+64];
    float4 y0, y1;
    y0.x = (v0.x-mean)*rstd*g0.x + b0.x;
    y0.y = (v0.y-mean)*rstd*g0.y + b0.y;
    y0.z = (v0.z-mean)*rstd*g0.z + b0.z;
    y0.w = (v0.w-mean)*rstd*g0.w + b0.w;
    y1.x = (v1.x-mean)*rstd*g1.x + b1.x;
    y1.y = (v1.y-mean)*rstd*g1.y + b1.y;
    y1.z = (v1.z-mean)*rstd*g1.z + b1.z;
    y1.w = (v1.w-mean)*rstd*g1.w + b1.w;
    ushort4 o0, o1;
    o0.x = f2bits(y0.x); o0.y = f2bits(y0.y); o0.z = f2bits(y0.z); o0.w = f2bits(y0.w);
    o1.x = f2bits(y1.x); o1.y = f2bits(y1.y); o1.z = f2bits(y1.z); o1.w = f2bits(y1.w);
    ushort4* yr = (ushort4*)(y + (size_t)row * DIM);
    yr[lane] = o0; yr[lane+64] = o1;
    *(float4*)&T[wave][lane*4]       = y0;
    *(float4*)&T[wave][256 + lane*4] = y1;
    __syncthreads();
    const int d0 = threadIdx.x;   // 0..255, handles d0 and d0+256
    const float m0 = (T[0][d0]     + T[1][d0]     + T[2][d0]     + T[3][d0])     * 0.25f;
    const float m1 = (T[0][d0+256] + T[1][d0+256] + T[2][d0+256] + T[3][d0+256]) * 0.25f;
    u16* gr = G + ((size_t)bb*NN + n)*DIM;
    gr[d0]       = f2bits(m0);
    gr[d0 + 256] = f2bits(m1);
}

// ---------- fused s_attn + gating + residual + NEXT layer's ln1 ----------
__global__ __launch_bounds__(256)
void fuse2_kernel(const float4* __restrict__ xb, const float4* __restrict__ m1,
                  const u16* __restrict__ ca, const u16* __restrict__ xl,
                  const u16* __restrict__ xg, const float* __restrict__ wsv,
                  const float* __restrict__ bs, float4* __restrict__ xa,
                  const float* __restrict__ lng, const float* __restrict__ lnb,
                  u16* __restrict__ lnout)
{
    const int wave = threadIdx.x >> 6, lane = threadIdx.x & 63;
    const int row = blockIdx.x * 4 + wave;
    const int b = row >> 10, n = row & 255;
    const u16* xlr = xl + (size_t)row * RED;
    const u16* xgr = xg + ((size_t)b*NN + n) * RED;
    float s = bits2f(xlr[lane])    * wsv[lane]
            + bits2f(xlr[lane+64]) * wsv[lane+64]
            + bits2f(xgr[lane])    * wsv[RED+lane]
            + bits2f(xgr[lane+64]) * wsv[RED+64+lane];
#pragma unroll
    for (int off = 32; off; off >>= 1) s += __shfl_xor(s, off);
    s = 1.f / (1.f + __expf(-(s + bs[0])));
    const u16* car = ca + ((((size_t)b << 8) + n)*DIM);

    float4 o0, o1;
    {
        const size_t idx = (size_t)row*128 + lane;
        ushort4 cu = *(const ushort4*)(car + lane*4);
        float4 xv = xb[idx], mv = m1[idx];
        o0.x = xv.x + mv.x * bits2f(cu.x) * s;
        o0.y = xv.y + mv.y * bits2f(cu.y) * s;
        o0.z = xv.z + mv.z * bits2f(cu.z) * s;
        o0.w = xv.w + mv.w * bits2f(cu.w) * s;
        xa[idx] = o0;
    }
    {
        const size_t idx = (size_t)row*128 + lane + 64;
        ushort4 cu = *(const ushort4*)(car + (lane + 64)*4);
        float4 xv = xb[idx], mv = m1[idx];
        o1.x = xv.x + mv.x * bits2f(cu.x) * s;
        o1.y = xv.y + mv.y * bits2f(cu.y) * s;
        o1.z = xv.z + mv.z * bits2f(cu.z) * s;
        o1.w = xv.w + mv.w * bits2f(cu.w) * s;
        xa[idx] = o1;
    }

    if (lnout) {   // next layer's ln1, computed from the row already in registers
        float t  = o0.x+o0.y+o0.z+o0.w + o1.x+o1.y+o1.z+o1.w;
        float t2 = o0.x*o0.x+o0.y*o0.y+o0.z*o0.z+o0.w*o0.w
                 + o1.x*o1.x+o1.y*o1.y+o1.z*o1.z+o1.w*o1.w;
#pragma unroll
        for (int off = 32; off; off >>= 1) { t += __shfl_xor(t, off); t2 += __shfl_xor(t2, off); }
        const float mean = t * (1.f/512.f);
        const float var  = t2 * (1.f/512.f) - mean*mean;
        const float rstd = rsqrtf(var + 1e-5f);
        const float4* gp = (const float4*)lng; const float4* bp = (const float4*)lnb;
        float4 g0 = gp[lane], g1 = gp[lane+64], b0 = bp[lane], b1 = bp[lane+64];
        ushort4 q0, q1;
        q0.x = f2bits((o0.x-mean)*rstd*g0.x + b0.x);
        q0.y = f2bits((o0.y-mean)*rstd*g0.y + b0.y);
        q0.z = f2bits((o0.z-mean)*rstd*g0.z + b0.z);
        q0.w = f2bits((o0.w-mean)*rstd*g0.w + b0.w);
        q1.x = f2bits((o1.x-mean)*rstd*g1.x + b1.x);
        q1.y = f2bits((o1.y-mean)*rstd*g1.y + b1.y);
        q1.z = f2bits((o1.z-mean)*rstd*g1.z + b1.z);
        q1.w = f2bits((o1.w-mean)*rstd*g1.w + b1.w);
        ushort4* yr = (ushort4*)(lnout + (size_t)row * DIM);
        yr[lane] = q0; yr[lane+64] = q1;
    }
}

// ---------- host launch ----------
extern "C" void kernel_launch(void* const* d_in, const int* in_sizes, int n_in,
                              void* d_out, int out_size, void* d_ws, size_t ws_size,
                              hipStream_t stream)
{
    const float* x_in  = (const float*)d_in[0];
    const float* ln1_g = (const float*)d_in[1];
    const float* ln1_b = (const float*)d_in[2];
    const float* w_qkv = (const float*)d_in[3];
    const float* w_o   = (const float*)d_in[4];
    const float* b_o   = (const float*)d_in[5];
    const float* ln2_g = (const float*)d_in[6];
    const float* ln2_b = (const float*)d_in[7];
    const float* w1    = (const float*)d_in[8];
    const float* b1    = (const float*)d_in[9];
    const float* w2    = (const float*)d_in[10];
    const float* b2    = (const float*)d_in[11];
    const float* bn_g  = (const float*)d_in[12];
    const float* bn_b  = (const float*)d_in[13];
    const float* wg    = (const float*)d_in[14];
    const float* bg    = (const float*)d_in[15];
    const float* wl    = (const float*)d_in[16];
    const float* bl    = (const float*)d_in[17];
    const float* wc    = (const float*)d_in[18];
    const float* bc    = (const float*)d_in[19];
    const float* wsw   = (const float*)d_in[20];
    const float* bsb   = (const float*)d_in[21];

    char* ws = (char*)d_ws;
    auto alloc = [&](size_t bytes) {
        char* p = ws;
        ws += (bytes + 255) & ~(size_t)255;
        return p;
    };
    float* XA = (float*)alloc(XELEMS * 4);
    float* XB = (float*)alloc(XELEMS * 4);
    float* M1 = (float*)alloc(XELEMS * 4);
    u16*   L  = (u16*)  alloc(XELEMS * 2);
    u16*   Q  = (u16*)  alloc((size_t)ROWS * 3*DIM * 2);
    u16*   H  = (u16*)  alloc((size_t)ROWS * MLPD * 2);
    u16*   G  = (u16*)  alloc((size_t)BB*NN*DIM * 2);
    u16*   G2 = (u16*)  alloc((size_t)BB*NN*RED * 2);
    u16*   XL = (u16*)  alloc((size_t)ROWS*RED * 2);
    u16*   CA = (u16*)  alloc((size_t)BB*NN*DIM * 2);
    // all-layer transposed bf16 weights
    u16* WTqkv = (u16*)alloc((size_t)DEPTH*DIM*3*DIM * 2);
    u16* WTo   = (u16*)alloc((size_t)DEPTH*DIM*DIM * 2);
    u16* WT1   = (u16*)alloc((size_t)DEPTH*DIM*MLPD * 2);
    u16* WT2   = (u16*)alloc((size_t)DEPTH*MLPD*DIM * 2);
    u16* WTl   = (u16*)alloc((size_t)DEPTH*DIM*RED * 2);
    u16* WTg   = (u16*)alloc((size_t)DEPTH*DIM*RED * 2);
    u16* WTc   = (u16*)alloc((size_t)DEPTH*RED*DIM * 2);

    // ---- all weight transposes in ONE launch (segmented grid) ----
    wtrans_fused<<<dim3(3264, 1, DEPTH), 256, 0, stream>>>(
        w_qkv, WTqkv, w_o, WTo, w1, WT1, w2, WT2, wl, WTl, wg, WTg, wc, WTc);

    // layer-0 attention LN (reads the external input); layers 1-3 get L from fuse2
    ln_kernel<<<ROWS/4, 256, 0, stream>>>(x_in, ln1_g, ln1_b, L, ROWS);

    for (int l = 0; l < DEPTH; ++l) {
        const float* Xres = l ? (const float*)XA : x_in;
        // ---- attention block ----
        gemm_cb<64,64,64,2,2><<<dim3(128,24), 256, 0, stream>>>(
            L, WTqkv + (size_t)l*DIM*3*DIM, nullptr, nullptr, Q, ROWS, 3*DIM, DIM, 0, 0);
        attn_mfma<<<BB*PP*HEADS*4, 256, 0, stream>>>(Q, L);
        gemm_db<64,64,64,2,2><<<dim3(128,8), 256, 0, stream>>>(
            L, WTo + (size_t)l*DIM*DIM, b_o + l*DIM, Xres, XB, ROWS, DIM, DIM, 0, 1);

        // ---- MLP ----
        ln_kernel<<<ROWS/4, 256, 0, stream>>>(XB, ln2_g + l*DIM, ln2_b + l*DIM, Q, ROWS);
        gemm_cb<64,64,64,2,2><<<dim3(128,32), 256, 0, stream>>>(
            Q, WT1 + (size_t)l*DIM*MLPD, b1 + l*MLPD, nullptr, H, ROWS, MLPD, DIM, 1, 0);
        gemm_db<64,64,64,2,2><<<dim3(128,8), 256, 0, stream>>>(
            H, WT2 + (size_t)l*MLPD*DIM, b2 + l*DIM, nullptr, M1, ROWS, DIM, MLPD, 0, 1);

        // ---- BiAttn ----
        lnmean_kernel<<<BB*NN, 256, 0, stream>>>(M1, bn_g + l*DIM, bn_b + l*DIM, L, G);
        gemm_wlg<<<320, 256, 0, stream>>>(L, G, WTl + (size_t)l*DIM*RED,
                                          WTg + (size_t)l*DIM*RED,
                                          bl + l*RED, bg + l*RED, XL, G2);
        gemm_db<64,64,64,2,2><<<dim3(32,8), 256, 0, stream>>>(
            G2, WTc + (size_t)l*RED*DIM, bc + l*DIM, nullptr, CA, BB*NN, DIM, RED, 2, 0);
        // fused s_attn + gating + residual (+ next layer's ln1 for l<3)
        const int last = (l == DEPTH-1);
        fuse2_kernel<<<ROWS/4, 256, 0, stream>>>(
            (const float4*)XB, (const float4*)M1, CA, XL, G2,
            wsw + (size_t)l*2*RED, bsb + l,
            last ? (float4*)d_out : (float4*)XA,
            ln1_g + (l+1)*DIM, ln1_b + (l+1)*DIM,
            last ? nullptr : L);
    }
}

// Round 13
// 797.849 us; speedup vs baseline: 1.0808x; 1.0228x over previous
//
#include <hip/hip_runtime.h>
#include <hip/hip_bf16.h>
#include <math.h>

typedef __hip_bfloat16 bf16;
typedef unsigned short u16;
typedef __bf16 bf16x8 __attribute__((ext_vector_type(8)));
typedef float f32x4 __attribute__((ext_vector_type(4)));

// ---------- helpers ----------
__device__ __forceinline__ float b2f(bf16 v) { return __bfloat162float(v); }
__device__ __forceinline__ bf16 f2b(float v) { return __float2bfloat16(v); }
__device__ __forceinline__ float bits2f(unsigned int u) {
    union { unsigned int i; float f; } w; w.i = u << 16; return w.f;
}
__device__ __forceinline__ u16 f2bits(float v) {
    union { bf16 h; u16 u; } w; w.h = __float2bfloat16(v); return w.u;
}
__device__ __forceinline__ void async16(void* lds, const void* g) {
    __builtin_amdgcn_global_load_lds(
        (const __attribute__((address_space(1))) unsigned int*)g,
        (__attribute__((address_space(3))) unsigned int*)lds, 16, 0, 0);
}

#define DEPTH 4
#define HEADS 8
#define DHEAD 64
#define DIM 512
#define MLPD 2048
#define RED 128
#define BB 8
#define PP 4
#define NN 256
#define ROWS (BB*PP*NN)          // 8192 tokens
#define XELEMS ((size_t)ROWS*DIM) // 4194304

// ---------- fused batched weight transpose+cast, ALL 7 weights in one launch ----------
__global__ __launch_bounds__(256)
void wtrans_fused(const float* __restrict__ Wqkv, u16* __restrict__ Tqkv,
                  const float* __restrict__ Wo,   u16* __restrict__ To,
                  const float* __restrict__ W1,   u16* __restrict__ T1,
                  const float* __restrict__ W2,   u16* __restrict__ T2,
                  const float* __restrict__ Wl,   u16* __restrict__ Tl,
                  const float* __restrict__ Wg,   u16* __restrict__ Tg,
                  const float* __restrict__ Wc,   u16* __restrict__ Tc)
{
    __shared__ float T[32][33];
    const int x = blockIdx.x, l = blockIdx.z;
    const float* W; u16* WT; int K, N, nx, local;
    if      (x < 768)  { W=Wqkv; WT=Tqkv; K=512;  N=1536; nx=48; local=x; }
    else if (x < 1024) { W=Wo;   WT=To;   K=512;  N=512;  nx=16; local=x-768; }
    else if (x < 2048) { W=W1;   WT=T1;   K=512;  N=2048; nx=64; local=x-1024; }
    else if (x < 3072) { W=W2;   WT=T2;   K=2048; N=512;  nx=16; local=x-2048; }
    else if (x < 3136) { W=Wl;   WT=Tl;   K=512;  N=128;  nx=4;  local=x-3072; }
    else if (x < 3200) { W=Wg;   WT=Tg;   K=512;  N=128;  nx=4;  local=x-3136; }
    else               { W=Wc;   WT=Tc;   K=128;  N=512;  nx=16; local=x-3200; }
    W  += (size_t)l * K * N;
    WT += (size_t)l * N * K;
    const int n0 = (local % nx) * 32, k0 = (local / nx) * 32;
    const int tx = threadIdx.x & 31, ty = threadIdx.x >> 5;
#pragma unroll
    for (int r = 0; r < 4; ++r)
        T[ty + r*8][tx] = W[(size_t)(k0 + ty + r*8) * N + n0 + tx];
    __syncthreads();
#pragma unroll
    for (int r = 0; r < 4; ++r)
        WT[(size_t)(n0 + ty + r*8) * K + k0 + tx] = f2bits(T[tx][ty + r*8]);
}

// ---------- counted-barrier 2-phase MFMA GEMM: C = act(A @ WT^T + bias) [+res]
// Raw s_barrier + counted vmcnt(CPT): previous tile's loads stay in flight for a
// full iteration instead of being drained right after issue. Verified round 12:
// W1 46->42.7 us, FETCH 16.4->13.7 GB vs the __syncthreads full-drain version.
template<int BM, int BN, int BK, int WROWS, int WCOLS>
__global__ __launch_bounds__(256)
void gemm_cb(const u16* __restrict__ A, const u16* __restrict__ WT,
             const float* __restrict__ bias, const float* __restrict__ res,
             void* __restrict__ Cv, int M, int N, int K, int act, int outf32)
{
    constexpr int KG  = BK/8;
    constexpr int RPC = 512/BK;
    constexpr int NCA = BM*BK/512;
    constexpr int NCB = BN*BK/512;
    constexpr int CPT = (NCA+NCB)/4;
    constexpr int WM = BM/WROWS, WN = BN/WCOLS;
    constexpr int AM = WM/16, AN = WN/16, KB = BK/32;

    __shared__ u16 As[2][BM*BK];
    __shared__ u16 Bs[2][BN*BK];
    const int tid = threadIdx.x, wave = tid >> 6, lane = tid & 63;
    const int bm = blockIdx.x * BM;
    const int bn = blockIdx.y * BN;
    const int wm = (wave / WCOLS) * WM, wn = (wave % WCOLS) * WN;
    const int lr = lane & 15, quad = lane >> 4;

    const int rowc = lane / KG;
    const int kgs  = ((lane & (KG-1)) ^ (KG == 4 ? ((rowc >> 1) & 3) : (rowc & 7))) * 8;

    auto stage = [&](int buf, int k0) {
#pragma unroll
        for (int t = 0; t < CPT; ++t) {
            const int c = wave*CPT + t;
            if (c < NCA)
                async16(&As[buf][c*512], A  + (size_t)(bm + c*RPC + rowc) * K + k0 + kgs);
            else
                async16(&Bs[buf][(c-NCA)*512], WT + (size_t)(bn + (c-NCA)*RPC + rowc) * K + k0 + kgs);
        }
    };

    f32x4 acc[AM][AN] = {};

    stage(0, 0);
    const int NK = K / BK;
    for (int ki = 0; ki < NK; ++ki) {
        const int cur = ki & 1;
        if (ki + 1 < NK) {
            stage(cur ^ 1, (ki + 1) * BK);   // issue next tile FIRST
            // counted wait: retire only tile ki's CPT loads; next tile's stay in flight
            if constexpr (CPT == 2)      asm volatile("s_waitcnt vmcnt(2)" ::: "memory");
            else if constexpr (CPT == 4) asm volatile("s_waitcnt vmcnt(4)" ::: "memory");
            else                          asm volatile("s_waitcnt vmcnt(0)" ::: "memory");
        } else {
            asm volatile("s_waitcnt vmcnt(0)" ::: "memory");
        }
        __builtin_amdgcn_s_barrier();        // all waves past their vmcnt -> tile ki ready

        bf16x8 af[AM][KB], bv[AN][KB];
#pragma unroll
        for (int i = 0; i < AM; ++i) {
            const int rA = wm + i*16 + lr;
            const int sw = (KG == 4 ? (((rA & 15) >> 1) & 3) : (rA & 7));
#pragma unroll
            for (int kb = 0; kb < KB; ++kb)
                af[i][kb] = *(const bf16x8*)(As[cur] + rA*BK + (((kb*4 + quad) ^ sw) * 8));
        }
#pragma unroll
        for (int j = 0; j < AN; ++j) {
            const int rB = wn + j*16 + lr;
            const int sw = (KG == 4 ? (((rB & 15) >> 1) & 3) : (rB & 7));
#pragma unroll
            for (int kb = 0; kb < KB; ++kb)
                bv[j][kb] = *(const bf16x8*)(Bs[cur] + rB*BK + (((kb*4 + quad) ^ sw) * 8));
        }
#pragma unroll
        for (int i = 0; i < AM; ++i)
#pragma unroll
            for (int j = 0; j < AN; ++j)
#pragma unroll
                for (int kb = 0; kb < KB; ++kb)
                    acc[i][j] = __builtin_amdgcn_mfma_f32_16x16x32_bf16(
                        af[i][kb], bv[j][kb], acc[i][j], 0, 0, 0);
        __builtin_amdgcn_s_barrier();        // reads consumed into regs; cur may be overwritten
    }

#pragma unroll
    for (int i = 0; i < AM; ++i) {
        const int rowb = bm + wm + i*16 + quad*4;
#pragma unroll
        for (int j = 0; j < AN; ++j) {
            const int col = bn + wn + j*16 + lr;
            const float bvs = bias ? bias[col] : 0.f;
#pragma unroll
            for (int r = 0; r < 4; ++r) {
                float v = acc[i][j][r] + bvs;
                if (act == 1) v = 0.5f * v * (1.0f + erff(v * 0.70710678118f));
                else if (act == 2) v = 1.0f / (1.0f + __expf(-v));
                const size_t idx = (size_t)(rowb + r) * N + col;
                if (res) v += res[idx];
                if (outf32) ((float*)Cv)[idx] = v;
                else        ((u16*)Cv)[idx] = f2bits(v);
            }
        }
    }
}

// ---------- horizontal-fused wl+wg GEMM: gelu(A @ W^T + b), K=512, N=128, bf16 out ----
// Counted-barrier schedule (same as gemm_cb, CPT=4).
__global__ __launch_bounds__(256)
void gemm_wlg(const u16* __restrict__ L, const u16* __restrict__ G,
              const u16* __restrict__ WTl, const u16* __restrict__ WTg,
              const float* __restrict__ bl, const float* __restrict__ bg,
              u16* __restrict__ XL, u16* __restrict__ G2)
{
    constexpr int K = 512, N = 128;
    const u16* A; const u16* WT; const float* bias; u16* C;
    int bm, bn;
    const int blk = blockIdx.x;
    if (blk < 256) { A = L; WT = WTl; bias = bl; C = XL;
                     bm = (blk & 127) * 64; bn = (blk >> 7) * 64; }
    else           { const int b2 = blk - 256; A = G; WT = WTg; bias = bg; C = G2;
                     bm = (b2 & 31) * 64; bn = (b2 >> 5) * 64; }

    __shared__ u16 As[2][64*64];
    __shared__ u16 Bs[2][64*64];
    const int tid = threadIdx.x, wave = tid >> 6, lane = tid & 63;
    const int wm = (wave >> 1) * 32, wn = (wave & 1) * 32;
    const int lr = lane & 15, quad = lane >> 4;

    const int rowc = lane >> 3;
    const int kgs  = ((lane & 7) ^ (rowc & 7)) * 8;

    auto stage = [&](int buf, int k0) {
#pragma unroll
        for (int t = 0; t < 4; ++t) {
            const int c = wave*4 + t;
            if (c < 8) async16(&As[buf][c*512], A  + (size_t)(bm + c*8 + rowc) * K + k0 + kgs);
            else       async16(&Bs[buf][(c-8)*512], WT + (size_t)(bn + (c-8)*8 + rowc) * K + k0 + kgs);
        }
    };

    f32x4 acc[2][2] = {};
    stage(0, 0);

    for (int ki = 0; ki < 8; ++ki) {
        const int cur = ki & 1;
        if (ki + 1 < 8) {
            stage(cur ^ 1, (ki + 1) * 64);
            asm volatile("s_waitcnt vmcnt(4)" ::: "memory");
        } else {
            asm volatile("s_waitcnt vmcnt(0)" ::: "memory");
        }
        __builtin_amdgcn_s_barrier();

        bf16x8 af[2][2], bv[2][2];
#pragma unroll
        for (int i = 0; i < 2; ++i) {
            const int rA = wm + i*16 + lr;
            const int sw = rA & 7;
#pragma unroll
            for (int kb = 0; kb < 2; ++kb)
                af[i][kb] = *(const bf16x8*)(As[cur] + rA*64 + (((kb*4 + quad) ^ sw) * 8));
        }
#pragma unroll
        for (int j = 0; j < 2; ++j) {
            const int rB = wn + j*16 + lr;
            const int sw = rB & 7;
#pragma unroll
            for (int kb = 0; kb < 2; ++kb)
                bv[j][kb] = *(const bf16x8*)(Bs[cur] + rB*64 + (((kb*4 + quad) ^ sw) * 8));
        }
#pragma unroll
        for (int i = 0; i < 2; ++i)
#pragma unroll
            for (int j = 0; j < 2; ++j)
#pragma unroll
                for (int kb = 0; kb < 2; ++kb)
                    acc[i][j] = __builtin_amdgcn_mfma_f32_16x16x32_bf16(
                        af[i][kb], bv[j][kb], acc[i][j], 0, 0, 0);
        __builtin_amdgcn_s_barrier();
    }

#pragma unroll
    for (int i = 0; i < 2; ++i) {
        const int rowb = bm + wm + i*16 + quad*4;
#pragma unroll
        for (int j = 0; j < 2; ++j) {
            const int col = bn + wn + j*16 + lr;
            const float bvs = bias[col];
#pragma unroll
            for (int r = 0; r < 4; ++r) {
                float v = acc[i][j][r] + bvs;
                v = 0.5f * v * (1.0f + erff(v * 0.70710678118f));
                C[(size_t)(rowb + r) * N + col] = f2bits(v);
            }
        }
    }
}

// ---------- MFMA flash attention, 4-way split-Q: one block per (b,p,h,qquarter) ----------
__global__ __launch_bounds__(256)
void attn_mfma(const u16* __restrict__ qkv, u16* __restrict__ out)
{
    __shared__ u16 Kt[64*72];
    __shared__ u16 Vt[64*72];
    __shared__ u16 Pw[4][16*72];
    const int tid = threadIdx.x;
    const int wave = tid >> 6, lane = tid & 63;
    const int lr = lane & 15, quad = lane >> 4;
    const int bp = blockIdx.x >> 5;          // (b,p)
    const int h  = (blockIdx.x >> 2) & 7;    // head
    const int qq = blockIdx.x & 3;           // query quarter
    const u16* base = qkv + (size_t)bp * NN * (3*DIM);
    const int qo = h*DHEAD, ko = DIM + h*DHEAD, vo = 2*DIM + h*DHEAD;
    const int m0 = qq*64 + wave*16;

    bf16x8 qf[2];
#pragma unroll
    for (int kb = 0; kb < 2; ++kb)
        qf[kb] = *(const bf16x8*)(base + (size_t)(m0 + lr)*(3*DIM) + qo + kb*32 + quad*8);

    f32x4 o[4] = {};
    float mrow[4], lrow[4];
#pragma unroll
    for (int r = 0; r < 4; ++r) { mrow[r] = -1e30f; lrow[r] = 0.f; }

    const int sr = tid >> 3, sc = tid & 7;

    for (int t = 0; t < 4; ++t) {
        __syncthreads();
#pragma unroll
        for (int half = 0; half < 2; ++half) {
            const int key = half*32 + sr;
            const u16* krow = base + (size_t)(t*64 + key)*(3*DIM);
            uint4 kv = *(const uint4*)(krow + ko + sc*8);
            *(uint4*)(Kt + key*72 + sc*8) = kv;
            uint4 vv = *(const uint4*)(krow + vo + sc*8);
            const int d0 = sc*8;
            Vt[(d0+0)*72 + key] = (u16)(vv.x & 0xffffu);
            Vt[(d0+1)*72 + key] = (u16)(vv.x >> 16);
            Vt[(d0+2)*72 + key] = (u16)(vv.y & 0xffffu);
            Vt[(d0+3)*72 + key] = (u16)(vv.y >> 16);
            Vt[(d0+4)*72 + key] = (u16)(vv.z & 0xffffu);
            Vt[(d0+5)*72 + key] = (u16)(vv.z >> 16);
            Vt[(d0+6)*72 + key] = (u16)(vv.w & 0xffffu);
            Vt[(d0+7)*72 + key] = (u16)(vv.w >> 16);
        }
        __syncthreads();

        f32x4 s[4] = {};
        bf16x8 kf[4][2];
#pragma unroll
        for (int j = 0; j < 4; ++j)
#pragma unroll
            for (int kb = 0; kb < 2; ++kb)
                kf[j][kb] = *(const bf16x8*)(Kt + (j*16 + lr)*72 + kb*32 + quad*8);
#pragma unroll
        for (int j = 0; j < 4; ++j)
#pragma unroll
            for (int kb = 0; kb < 2; ++kb)
                s[j] = __builtin_amdgcn_mfma_f32_16x16x32_bf16(
                    qf[kb], kf[j][kb], s[j], 0, 0, 0);

        float alpha[4];
#pragma unroll
        for (int r = 0; r < 4; ++r) {
#pragma unroll
            for (int j = 0; j < 4; ++j) s[j][r] *= 0.125f;
            float mt = fmaxf(fmaxf(s[0][r], s[1][r]), fmaxf(s[2][r], s[3][r]));
#pragma unroll
            for (int off = 1; off <= 8; off <<= 1) mt = fmaxf(mt, __shfl_xor(mt, off));
            const float mn = fmaxf(mrow[r], mt);
            alpha[r] = __expf(mrow[r] - mn);
            mrow[r] = mn;
            float ssum = 0.f;
#pragma unroll
            for (int j = 0; j < 4; ++j) {
                const float p = __expf(s[j][r] - mn);
                s[j][r] = p; ssum += p;
            }
#pragma unroll
            for (int off = 1; off <= 8; off <<= 1) ssum += __shfl_xor(ssum, off);
            lrow[r] = lrow[r]*alpha[r] + ssum;
        }

#pragma unroll
        for (int j = 0; j < 4; ++j)
#pragma unroll
            for (int r = 0; r < 4; ++r)
                Pw[wave][(quad*4 + r)*72 + j*16 + lr] = f2bits(s[j][r]);
        __syncthreads();

#pragma unroll
        for (int jd = 0; jd < 4; ++jd)
#pragma unroll
            for (int r = 0; r < 4; ++r)
                o[jd][r] *= alpha[r];

        bf16x8 af[2], bv[4][2];
#pragma unroll
        for (int kb = 0; kb < 2; ++kb)
            af[kb] = *(const bf16x8*)(Pw[wave] + lr*72 + kb*32 + quad*8);
#pragma unroll
        for (int jd = 0; jd < 4; ++jd)
#pragma unroll
            for (int kb = 0; kb < 2; ++kb)
                bv[jd][kb] = *(const bf16x8*)(Vt + (jd*16 + lr)*72 + kb*32 + quad*8);
#pragma unroll
        for (int jd = 0; jd < 4; ++jd)
#pragma unroll
            for (int kb = 0; kb < 2; ++kb)
                o[jd] = __builtin_amdgcn_mfma_f32_16x16x32_bf16(
                    af[kb], bv[jd][kb], o[jd], 0, 0, 0);
    }

#pragma unroll
    for (int r = 0; r < 4; ++r) {
        const float inv = 1.0f / lrow[r];
        const size_t rowg = (size_t)bp*NN + m0 + quad*4 + r;
#pragma unroll
        for (int jd = 0; jd < 4; ++jd)
            out[rowg*DIM + h*DHEAD + jd*16 + lr] = f2bits(o[jd][r] * inv);
    }
}

// ---------- LayerNorm over DIM=512, fp32 in, bf16 out; one wave per row; float4 ----------
__global__ __launch_bounds__(256)
void ln_kernel(const float* __restrict__ x, const float* __restrict__ g,
               const float* __restrict__ b, u16* __restrict__ y, int rows)
{
    const int wave = threadIdx.x >> 6, lane = threadIdx.x & 63;
    const int row = blockIdx.x * 4 + wave;
    if (row >= rows) return;
    const float4* xr = (const float4*)(x + (size_t)row * DIM);
    float4 v0 = xr[lane], v1 = xr[lane + 64];
    float s  = v0.x+v0.y+v0.z+v0.w + v1.x+v1.y+v1.z+v1.w;
    float s2 = v0.x*v0.x+v0.y*v0.y+v0.z*v0.z+v0.w*v0.w
             + v1.x*v1.x+v1.y*v1.y+v1.z*v1.z+v1.w*v1.w;
#pragma unroll
    for (int off = 32; off; off >>= 1) { s += __shfl_xor(s, off); s2 += __shfl_xor(s2, off); }
    const float mean = s * (1.f/512.f);
    const float var  = s2 * (1.f/512.f) - mean*mean;
    const float rstd = rsqrtf(var + 1e-5f);
    const float4* gp = (const float4*)g; const float4* bp = (const float4*)b;
    float4 g0 = gp[lane], g1 = gp[lane+64], b0 = bp[lane], b1 = bp[lane+64];
    ushort4 o0, o1;
    o0.x = f2bits((v0.x-mean)*rstd*g0.x + b0.x);
    o0.y = f2bits((v0.y-mean)*rstd*g0.y + b0.y);
    o0.z = f2bits((v0.z-mean)*rstd*g0.z + b0.z);
    o0.w = f2bits((v0.w-mean)*rstd*g0.w + b0.w);
    o1.x = f2bits((v1.x-mean)*rstd*g1.x + b1.x);
    o1.y = f2bits((v1.y-mean)*rstd*g1.y + b1.y);
    o1.z = f2bits((v1.z-mean)*rstd*g1.z + b1.z);
    o1.w = f2bits((v1.w-mean)*rstd*g1.w + b1.w);
    ushort4* yr = (ushort4*)(y + (size_t)row * DIM);
    yr[lane] = o0; yr[lane+64] = o1;
}

// ---------- fused BiAttn LN + mean over P: block=(b,n), wave p=0..3 ----------
__global__ __launch_bounds__(256)
void lnmean_kernel(const float* __restrict__ x, const float* __restrict__ g,
                   const float* __restrict__ b, u16* __restrict__ y,
                   u16* __restrict__ G)
{
    __shared__ float T[4][512];
    const int wave = threadIdx.x >> 6, lane = threadIdx.x & 63;
    const int bb = blockIdx.x >> 8, n = blockIdx.x & 255;
    const int row = (bb*PP + wave)*NN + n;
    const float4* xr = (const float4*)(x + (size_t)row * DIM);
    float4 v0 = xr[lane], v1 = xr[lane + 64];
    float s  = v0.x+v0.y+v0.z+v0.w + v1.x+v1.y+v1.z+v1.w;
    float s2 = v0.x*v0.x+v0.y*v0.y+v0.z*v0.z+v0.w*v0.w
             + v1.x*v1.x+v1.y*v1.y+v1.z*v1.z+v1.w*v1.w;
#pragma unroll
    for (int off = 32; off; off >>= 1) { s += __shfl_xor(s, off); s2 += __shfl_xor(s2, off); }
    const float mean = s * (1.f/512.f);
    const float var  = s2 * (1.f/512.f) - mean*mean;
    const float rstd = rsqrtf(var + 1e-5f);
    const float4* gp = (const float4*)g; const float4* bp = (const float4*)b;
    float4 g0 = gp[lane], g1 = gp[lane+64], b0 = bp[lane], b1 = bp[lane+64];
    float4 y0, y1;
    y0.x = (v0.x-mean)*rstd*g0.x + b0.x;
    y0.y = (v0.y-mean)*rstd*g0.y + b0.y;
    y0.z = (v0.z-mean)*rstd*g0.z + b0.z;
    y0.w = (v0.w-mean)*rstd*g0.w + b0.w;
    y1.x = (v1.x-mean)*rstd*g1.x + b1.x;
    y1.y = (v1.y-mean)*rstd*g1.y + b1.y;
    y1.z = (v1.z-mean)*rstd*g1.z + b1.z;
    y1.w = (v1.w-mean)*rstd*g1.w + b1.w;
    ushort4 o0, o1;
    o0.x = f2bits(y0.x); o0.y = f2bits(y0.y); o0.z = f2bits(y0.z); o0.w = f2bits(y0.w);
    o1.x = f2bits(y1.x); o1.y = f2bits(y1.y); o1.z = f2bits(y1.z); o1.w = f2bits(y1.w);
    ushort4* yr = (ushort4*)(y + (size_t)row * DIM);
    yr[lane] = o0; yr[lane+64] = o1;
    *(float4*)&T[wave][lane*4]       = y0;
    *(float4*)&T[wave][256 + lane*4] = y1;
    __syncthreads();
    const int d0 = threadIdx.x;   // 0..255, handles d0 and d0+256
    const float m0 = (T[0][d0]     + T[1][d0]     + T[2][d0]     + T[3][d0])     * 0.25f;
    const float m1 = (T[0][d0+256] + T[1][d0+256] + T[2][d0+256] + T[3][d0+256]) * 0.25f;
    u16* gr = G + ((size_t)bb*NN + n)*DIM;
    gr[d0]       = f2bits(m0);
    gr[d0 + 256] = f2bits(m1);
}

// ---------- fused s_attn + gating + residual + NEXT layer's ln1 ----------
__global__ __launch_bounds__(256)
void fuse2_kernel(const float4* __restrict__ xb, const float4* __restrict__ m1,
                  const u16* __restrict__ ca, const u16* __restrict__ xl,
                  const u16* __restrict__ xg, const float* __restrict__ wsv,
                  const float* __restrict__ bs, float4* __restrict__ xa,
                  const float* __restrict__ lng, const float* __restrict__ lnb,
                  u16* __restrict__ lnout)
{
    const int wave = threadIdx.x >> 6, lane = threadIdx.x & 63;
    const int row = blockIdx.x * 4 + wave;
    const int b = row >> 10, n = row & 255;
    const u16* xlr = xl + (size_t)row * RED;
    const u16* xgr = xg + ((size_t)b*NN + n) * RED;
    float s = bits2f(xlr[lane])    * wsv[lane]
            + bits2f(xlr[lane+64]) * wsv[lane+64]
            + bits2f(xgr[lane])    * wsv[RED+lane]
            + bits2f(xgr[lane+64]) * wsv[RED+64+lane];
#pragma unroll
    for (int off = 32; off; off >>= 1) s += __shfl_xor(s, off);
    s = 1.f / (1.f + __expf(-(s + bs[0])));
    const u16* car = ca + ((((size_t)b << 8) + n)*DIM);

    float4 o0, o1;
    {
        const size_t idx = (size_t)row*128 + lane;
        ushort4 cu = *(const ushort4*)(car + lane*4);
        float4 xv = xb[idx], mv = m1[idx];
        o0.x = xv.x + mv.x * bits2f(cu.x) * s;
        o0.y = xv.y + mv.y * bits2f(cu.y) * s;
        o0.z = xv.z + mv.z * bits2f(cu.z) * s;
        o0.w = xv.w + mv.w * bits2f(cu.w) * s;
        xa[idx] = o0;
    }
    {
        const size_t idx = (size_t)row*128 + lane + 64;
        ushort4 cu = *(const ushort4*)(car + (lane + 64)*4);
        float4 xv = xb[idx], mv = m1[idx];
        o1.x = xv.x + mv.x * bits2f(cu.x) * s;
        o1.y = xv.y + mv.y * bits2f(cu.y) * s;
        o1.z = xv.z + mv.z * bits2f(cu.z) * s;
        o1.w = xv.w + mv.w * bits2f(cu.w) * s;
        xa[idx] = o1;
    }

    if (lnout) {   // next layer's ln1, computed from the row already in registers
        float t  = o0.x+o0.y+o0.z+o0.w + o1.x+o1.y+o1.z+o1.w;
        float t2 = o0.x*o0.x+o0.y*o0.y+o0.z*o0.z+o0.w*o0.w
                 + o1.x*o1.x+o1.y*o1.y+o1.z*o1.z+o1.w*o1.w;
#pragma unroll
        for (int off = 32; off; off >>= 1) { t += __shfl_xor(t, off); t2 += __shfl_xor(t2, off); }
        const float mean = t * (1.f/512.f);
        const float var  = t2 * (1.f/512.f) - mean*mean;
        const float rstd = rsqrtf(var + 1e-5f);
        const float4* gp = (const float4*)lng; const float4* bp = (const float4*)lnb;
        float4 g0 = gp[lane], g1 = gp[lane+64], b0 = bp[lane], b1 = bp[lane+64];
        ushort4 q0, q1;
        q0.x = f2bits((o0.x-mean)*rstd*g0.x + b0.x);
        q0.y = f2bits((o0.y-mean)*rstd*g0.y + b0.y);
        q0.z = f2bits((o0.z-mean)*rstd*g0.z + b0.z);
        q0.w = f2bits((o0.w-mean)*rstd*g0.w + b0.w);
        q1.x = f2bits((o1.x-mean)*rstd*g1.x + b1.x);
        q1.y = f2bits((o1.y-mean)*rstd*g1.y + b1.y);
        q1.z = f2bits((o1.z-mean)*rstd*g1.z + b1.z);
        q1.w = f2bits((o1.w-mean)*rstd*g1.w + b1.w);
        ushort4* yr = (ushort4*)(lnout + (size_t)row * DIM);
        yr[lane] = q0; yr[lane+64] = q1;
    }
}

// ---------- host launch ----------
extern "C" void kernel_launch(void* const* d_in, const int* in_sizes, int n_in,
                              void* d_out, int out_size, void* d_ws, size_t ws_size,
                              hipStream_t stream)
{
    const float* x_in  = (const float*)d_in[0];
    const float* ln1_g = (const float*)d_in[1];
    const float* ln1_b = (const float*)d_in[2];
    const float* w_qkv = (const float*)d_in[3];
    const float* w_o   = (const float*)d_in[4];
    const float* b_o   = (const float*)d_in[5];
    const float* ln2_g = (const float*)d_in[6];
    const float* ln2_b = (const float*)d_in[7];
    const float* w1    = (const float*)d_in[8];
    const float* b1    = (const float*)d_in[9];
    const float* w2    = (const float*)d_in[10];
    const float* b2    = (const float*)d_in[11];
    const float* bn_g  = (const float*)d_in[12];
    const float* bn_b  = (const float*)d_in[13];
    const float* wg    = (const float*)d_in[14];
    const float* bg    = (const float*)d_in[15];
    const float* wl    = (const float*)d_in[16];
    const float* bl    = (const float*)d_in[17];
    const float* wc    = (const float*)d_in[18];
    const float* bc    = (const float*)d_in[19];
    const float* wsw   = (const float*)d_in[20];
    const float* bsb   = (const float*)d_in[21];

    char* ws = (char*)d_ws;
    auto alloc = [&](size_t bytes) {
        char* p = ws;
        ws += (bytes + 255) & ~(size_t)255;
        return p;
    };
    float* XA = (float*)alloc(XELEMS * 4);
    float* XB = (float*)alloc(XELEMS * 4);
    float* M1 = (float*)alloc(XELEMS * 4);
    u16*   L  = (u16*)  alloc(XELEMS * 2);
    u16*   Q  = (u16*)  alloc((size_t)ROWS * 3*DIM * 2);
    u16*   H  = (u16*)  alloc((size_t)ROWS * MLPD * 2);
    u16*   G  = (u16*)  alloc((size_t)BB*NN*DIM * 2);
    u16*   G2 = (u16*)  alloc((size_t)BB*NN*RED * 2);
    u16*   XL = (u16*)  alloc((size_t)ROWS*RED * 2);
    u16*   CA = (u16*)  alloc((size_t)BB*NN*DIM * 2);
    // all-layer transposed bf16 weights
    u16* WTqkv = (u16*)alloc((size_t)DEPTH*DIM*3*DIM * 2);
    u16* WTo   = (u16*)alloc((size_t)DEPTH*DIM*DIM * 2);
    u16* WT1   = (u16*)alloc((size_t)DEPTH*DIM*MLPD * 2);
    u16* WT2   = (u16*)alloc((size_t)DEPTH*MLPD*DIM * 2);
    u16* WTl   = (u16*)alloc((size_t)DEPTH*DIM*RED * 2);
    u16* WTg   = (u16*)alloc((size_t)DEPTH*DIM*RED * 2);
    u16* WTc   = (u16*)alloc((size_t)DEPTH*RED*DIM * 2);

    // ---- all weight transposes in ONE launch (segmented grid) ----
    wtrans_fused<<<dim3(3264, 1, DEPTH), 256, 0, stream>>>(
        w_qkv, WTqkv, w_o, WTo, w1, WT1, w2, WT2, wl, WTl, wg, WTg, wc, WTc);

    // layer-0 attention LN (reads the external input); layers 1-3 get L from fuse2
    ln_kernel<<<ROWS/4, 256, 0, stream>>>(x_in, ln1_g, ln1_b, L, ROWS);

    for (int l = 0; l < DEPTH; ++l) {
        const float* Xres = l ? (const float*)XA : x_in;
        // ---- attention block ----
        gemm_cb<64,64,64,2,2><<<dim3(128,24), 256, 0, stream>>>(
            L, WTqkv + (size_t)l*DIM*3*DIM, nullptr, nullptr, Q, ROWS, 3*DIM, DIM, 0, 0);
        attn_mfma<<<BB*PP*HEADS*4, 256, 0, stream>>>(Q, L);
        gemm_cb<64,64,64,2,2><<<dim3(128,8), 256, 0, stream>>>(
            L, WTo + (size_t)l*DIM*DIM, b_o + l*DIM, Xres, XB, ROWS, DIM, DIM, 0, 1);

        // ---- MLP ----
        ln_kernel<<<ROWS/4, 256, 0, stream>>>(XB, ln2_g + l*DIM, ln2_b + l*DIM, Q, ROWS);
        gemm_cb<64,64,64,2,2><<<dim3(128,32), 256, 0, stream>>>(
            Q, WT1 + (size_t)l*DIM*MLPD, b1 + l*MLPD, nullptr, H, ROWS, MLPD, DIM, 1, 0);
        gemm_cb<64,64,64,2,2><<<dim3(128,8), 256, 0, stream>>>(
            H, WT2 + (size_t)l*MLPD*DIM, b2 + l*DIM, nullptr, M1, ROWS, DIM, MLPD, 0, 1);

        // ---- BiAttn ----
        lnmean_kernel<<<BB*NN, 256, 0, stream>>>(M1, bn_g + l*DIM, bn_b + l*DIM, L, G);
        gemm_wlg<<<320, 256, 0, stream>>>(L, G, WTl + (size_t)l*DIM*RED,
                                          WTg + (size_t)l*DIM*RED,
                                          bl + l*RED, bg + l*RED, XL, G2);
        gemm_cb<64,64,64,2,2><<<dim3(32,8), 256, 0, stream>>>(
            G2, WTc + (size_t)l*RED*DIM, bc + l*DIM, nullptr, CA, BB*NN, DIM, RED, 2, 0);
        // fused s_attn + gating + residual (+ next layer's ln1 for l<3)
        const int last = (l == DEPTH-1);
        fuse2_kernel<<<ROWS/4, 256, 0, stream>>>(
            (const float4*)XB, (const float4*)M1, CA, XL, G2,
            wsw + (size_t)l*2*RED, bsb + l,
            last ? (float4*)d_out : (float4*)XA,
            ln1_g + (l+1)*DIM, ln1_b + (l+1)*DIM,
            last ? nullptr : L);
    }
}